// Round 9
// baseline (502.235 us; speedup 1.0000x reference)
//
#include <hip/hip_runtime.h>

#define H 64
#define EPB 4096        // edges per bin block (489 blocks)
#define BMAX 400        // >= bucket count (391)
#define ST 256          // taxon rows per bucket
#define SP 512          // palmprint rows per bucket
#define LSHT 18         // t-entry: (dst&255)<<18 | src
#define LSHP 17         // p-entry: (src&511)<<17 | dst
#define CAPB 5632       // bucket capacity (mean 5120 + 7 sigma); %4==0

typedef _Float16 half2v __attribute__((ext_vector_type(2)));
typedef _Float16 half8v __attribute__((ext_vector_type(8)));
typedef _Float16 f16x8  __attribute__((ext_vector_type(8)));
typedef float    f32x4  __attribute__((ext_vector_type(4)));
typedef int      i32x4  __attribute__((ext_vector_type(4)));

#if defined(__has_builtin)
#if __has_builtin(__builtin_amdgcn_fdot2)
#define HAS_FDOT2 1
#endif
#endif

#define MFMA16(a, b, c) __builtin_amdgcn_mfma_f32_16x16x32_f16(a, b, c, 0, 0, 0)

// ---- MFMA xt device body: C = A(f32)@W + bias + addend(f32), f16 out ----
__device__ __forceinline__ void mfma_xt_dev(const float* __restrict__ A,
                                            const float* __restrict__ W,
                                            const float* __restrict__ bias,
                                            const float* __restrict__ addend,
                                            _Float16* __restrict__ C,
                                            int N, int wid, int nwaves) {
    const int lane = threadIdx.x & 63;
    const int m = lane & 15, quad = lane >> 4;
    const int nTiles = (N + 15) >> 4;

    f16x8 wf[2][4];
#pragma unroll
    for (int kh = 0; kh < 2; ++kh)
#pragma unroll
        for (int nt = 0; nt < 4; ++nt) {
            f16x8 a;
#pragma unroll
            for (int j = 0; j < 8; ++j) {
                int k = kh * 32 + quad * 8 + j;
                a[j] = (_Float16)W[k * 64 + nt * 16 + m];
            }
            wf[kh][nt] = a;
        }
    float bv[4];
#pragma unroll
    for (int nt = 0; nt < 4; ++nt) bv[nt] = bias[nt * 16 + m];

    for (int t = wid; t < nTiles; t += nwaves) {
        int row = t * 16 + m;
        f16x8 alo = {}, ahi = {};
        if (row < N) {
            const f32x4* p = (const f32x4*)(A + (size_t)row * 64);
            f32x4 x0 = __builtin_nontemporal_load(p + quad * 2);
            f32x4 x1 = __builtin_nontemporal_load(p + quad * 2 + 1);
            f32x4 x2 = __builtin_nontemporal_load(p + 8 + quad * 2);
            f32x4 x3 = __builtin_nontemporal_load(p + 8 + quad * 2 + 1);
            alo[0] = (_Float16)x0[0]; alo[1] = (_Float16)x0[1];
            alo[2] = (_Float16)x0[2]; alo[3] = (_Float16)x0[3];
            alo[4] = (_Float16)x1[0]; alo[5] = (_Float16)x1[1];
            alo[6] = (_Float16)x1[2]; alo[7] = (_Float16)x1[3];
            ahi[0] = (_Float16)x2[0]; ahi[1] = (_Float16)x2[1];
            ahi[2] = (_Float16)x2[2]; ahi[3] = (_Float16)x2[3];
            ahi[4] = (_Float16)x3[0]; ahi[5] = (_Float16)x3[1];
            ahi[6] = (_Float16)x3[2]; ahi[7] = (_Float16)x3[3];
        }
#pragma unroll
        for (int nt = 0; nt < 4; ++nt) {
            f32x4 a1 = {0.f, 0.f, 0.f, 0.f};
            a1 = MFMA16(alo, wf[0][nt], a1);
            a1 = MFMA16(ahi, wf[1][nt], a1);
#pragma unroll
            for (int r = 0; r < 4; ++r) {
                int orow = t * 16 + quad * 4 + r;
                if (orow < N) {
                    float ad = __builtin_nontemporal_load(
                        &addend[(size_t)orow * 64 + nt * 16 + m]);
                    C[(size_t)orow * 64 + nt * 16 + m] = (_Float16)(a1[r] + bv[nt] + ad);
                }
            }
        }
    }
}

// in-place inclusive scan over sc[0..511] (counts pre-loaded), 256 threads
__device__ __forceinline__ void block_scan512(int* sc, int tid) {
    for (int off = 1; off < 512; off <<= 1) {
        int i0 = tid, i1 = tid + 256;
        int v0 = (i0 >= off) ? sc[i0 - off] : 0;
        int v1 = (i1 >= off) ? sc[i1 - off] : 0;
        __syncthreads();
        sc[i0] += v0;
        sc[i1] += v1;
        __syncthreads();
    }
}

// ---- K_A: fused [bin (LDS sort-then-stream) | xt GEMM | pemb cast] -----
__global__ void __launch_bounds__(256) k_bin_xt(
    const int* __restrict__ src, const int* __restrict__ dst,
    int* __restrict__ curT, int* __restrict__ curP,
    unsigned* __restrict__ binT, unsigned* __restrict__ binP,
    int BT, int BP, int E, int nbBin,
    const float* __restrict__ A, const float* __restrict__ W,
    const float* __restrict__ bias, const float* __restrict__ addend,
    _Float16* __restrict__ C, int NT_, int xtBlocks,
    const float* __restrict__ pembIn, _Float16* __restrict__ PhOut,
    int NP_, int castBlocks) {
    __shared__ int cT[BMAX], cP[BMAX], oT[BMAX], oP[BMAX], cur[BMAX];
    __shared__ int sc[512];
    __shared__ unsigned stage[EPB];
    int tid = threadIdx.x;
    if ((int)blockIdx.x >= nbBin + xtBlocks) {
        // pemb f32 -> f16 cast (read-once stream)
        int cb = blockIdx.x - nbBin - xtBlocks;
        int idx = cb * 256 + tid, stride = castBlocks * 256;
        int total = NP_ * 8;
        for (int i = idx; i < total; i += stride) {
            const f32x4* p = (const f32x4*)(pembIn + (size_t)i * 8);
            f32x4 x0 = __builtin_nontemporal_load(p);
            f32x4 x1 = __builtin_nontemporal_load(p + 1);
            f16x8 o;
            o[0] = (_Float16)x0[0]; o[1] = (_Float16)x0[1];
            o[2] = (_Float16)x0[2]; o[3] = (_Float16)x0[3];
            o[4] = (_Float16)x1[0]; o[5] = (_Float16)x1[1];
            o[6] = (_Float16)x1[2]; o[7] = (_Float16)x1[3];
            *(f16x8*)&PhOut[(size_t)i * 8] = o;
        }
        return;
    }
    if ((int)blockIdx.x >= nbBin) {
        int xb = blockIdx.x - nbBin;
        mfma_xt_dev(A, W, bias, addend, C, NT_, xb * 4 + (tid >> 6), xtBlocks * 4);
        return;
    }
    const int wave = tid >> 6, lane = tid & 63;
    for (int i = tid; i < BMAX; i += 256) { cT[i] = 0; cP[i] = 0; }
    __syncthreads();
    int e0 = blockIdx.x * EPB;
    int ls[EPB / 256], ld[EPB / 256];
#pragma unroll
    for (int k = 0; k < EPB / 256; ++k) {
        int i = e0 + k * 256 + tid;
        if (i < E) {
            ls[k] = __builtin_nontemporal_load(&src[i]);
            ld[k] = __builtin_nontemporal_load(&dst[i]);
            atomicAdd(&cT[ld[k] >> 8], 1);
            atomicAdd(&cP[ls[k] >> 9], 1);
        }
    }
    __syncthreads();
    // grab global chunks
    for (int b = tid; b < BT; b += 256) { int c = cT[b]; oT[b] = c ? atomicAdd(&curT[b], c) : 0; }
    for (int b = tid; b < BP; b += 256) { int c = cP[b]; oP[b] = c ? atomicAdd(&curP[b], c) : 0; }
    // ---- T side: scan, scatter to LDS, stream out ----
    sc[tid]       = (tid < BT) ? cT[tid] : 0;
    sc[tid + 256] = (tid + 256 < BT) ? cT[tid + 256] : 0;
    __syncthreads();
    block_scan512(sc, tid);
    for (int b = tid; b < BT; b += 256) cur[b] = sc[b] - cT[b];
    __syncthreads();
#pragma unroll
    for (int k = 0; k < EPB / 256; ++k) {
        int i = e0 + k * 256 + tid;
        if (i < E) {
            int bt = ld[k] >> 8;
            int pos = atomicAdd(&cur[bt], 1);
            stage[pos] = ((unsigned)(ld[k] & 255) << LSHT) | (unsigned)ls[k];
        }
    }
    __syncthreads();
    for (int b = wave; b < BT; b += 4) {
        int cnt = cT[b], so = sc[b] - cnt, go = oT[b];
        for (int i = lane; i < cnt; i += 64) {
            int pos = go + i;
            if (pos < CAPB) binT[(size_t)b * CAPB + pos] = stage[so + i];
        }
    }
    __syncthreads();
    // ---- P side ----
    sc[tid]       = (tid < BP) ? cP[tid] : 0;
    sc[tid + 256] = (tid + 256 < BP) ? cP[tid + 256] : 0;
    __syncthreads();
    block_scan512(sc, tid);
    for (int b = tid; b < BP; b += 256) cur[b] = sc[b] - cP[b];
    __syncthreads();
#pragma unroll
    for (int k = 0; k < EPB / 256; ++k) {
        int i = e0 + k * 256 + tid;
        if (i < E) {
            int bp = ls[k] >> 9;
            int pos = atomicAdd(&cur[bp], 1);
            stage[pos] = ((unsigned)(ls[k] & 511) << LSHP) | (unsigned)ld[k];
        }
    }
    __syncthreads();
    for (int b = wave; b < BP; b += 4) {
        int cnt = cP[b], so = sc[b] - cnt, go = oP[b];
        for (int i = lane; i < cnt; i += 64) {
            int pos = go + i;
            if (pos < CAPB) binP[(size_t)b * CAPB + pos] = stage[so + i];
        }
    }
}

// ---- CSR per-bucket device body: scatter into LDS, SORT rows, stream ---
// Per-row ascending sort => gathers in k_gg traverse the table in order,
// giving cross-wave temporal banding (instantaneous working set << table).
__device__ __forceinline__ void csr_dev(const unsigned* __restrict__ binned,
                                        const int* __restrict__ cur,
                                        int* __restrict__ start_g, int* __restrict__ cnt_g,
                                        int* __restrict__ adj,
                                        int S, int lshift, int N, int b,
                                        int* lcnt, int* lscan, int* lcur, int* adj_lds) {
    int tid = threadIdx.x;
    int base = b * CAPB;
    int n = cur[b]; if (n > CAPB) n = CAPB;
    int rowlo = b * S;
    unsigned nbmask = (1u << lshift) - 1u;

    for (int i = tid; i < S; i += 256) lcnt[i] = 0;
    __syncthreads();
    for (int i = tid; i < n; i += 256)
        atomicAdd(&lcnt[binned[base + i] >> lshift], 1);
    __syncthreads();
    for (int i = tid; i < S; i += 256) lscan[i] = lcnt[i];
    __syncthreads();
    for (int off = 1; off < S; off <<= 1) {
        int i0 = tid, i1 = tid + 256;
        int v0 = (i0 >= off) ? lscan[i0 - off] : 0;
        int v1 = (S > 256 && i1 >= off) ? lscan[i1 - off] : 0;
        __syncthreads();
        if (i0 < S) lscan[i0] += v0;
        if (S > 256 && i1 < S) lscan[i1] += v1;
        __syncthreads();
    }
    for (int r = tid; r < S; r += 256) {
        int ex = lscan[r] - lcnt[r];
        lcur[r] = ex;
        int row = rowlo + r;
        if (row < N) {
            start_g[row] = base + ex;
            cnt_g[row]   = lcnt[r];
        }
    }
    __syncthreads();
    for (int i = tid; i < n; i += 256) {
        unsigned e = binned[base + i];
        int r = e >> lshift;
        int pos = atomicAdd(&lcur[r], 1);
        adj_lds[pos] = (int)(e & nbmask);
    }
    __syncthreads();
    // per-row ascending insertion sort (one thread per row; sum order is
    // already nondeterministic from the atomic scatter, so this is safe)
    for (int r = tid; r < S; r += 256) {
        int lo = lscan[r] - lcnt[r], hi = lscan[r];
        for (int a = lo + 1; a < hi; ++a) {
            int key = adj_lds[a];
            int c = a - 1;
            while (c >= lo && adj_lds[c] > key) {
                adj_lds[c + 1] = adj_lds[c];
                --c;
            }
            adj_lds[c + 1] = key;
        }
    }
    __syncthreads();
    int n4 = n & ~3;
    for (int i = tid * 4; i < n4; i += 1024)
        *(int4*)&adj[base + i] = *(const int4*)&adj_lds[i];
    for (int i = n4 + tid; i < n; i += 256)
        adj[base + i] = adj_lds[i];
}

// ---- K_B: [csr-t | csr-p] ----------------------------------------------
__global__ void __launch_bounds__(256) k_csr(
    const unsigned* __restrict__ binT, const unsigned* __restrict__ binP,
    const int* __restrict__ curT, const int* __restrict__ curP,
    int* __restrict__ start_t, int* __restrict__ cnt_t, int* __restrict__ adj_t,
    int* __restrict__ start_p, int* __restrict__ cnt_p, int* __restrict__ adj_p,
    int BT, int BP, int NT_, int NP_) {
    __shared__ int lcnt[512], lscan[512], lcur[512];
    __shared__ int adj_lds[CAPB];
    int bi = blockIdx.x;
    if (bi < BT)
        csr_dev(binT, curT, start_t, cnt_t, adj_t, ST, LSHT, NT_, bi, lcnt, lscan, lcur, adj_lds);
    else
        csr_dev(binP, curP, start_p, cnt_p, adj_p, SP, LSHP, NP_, bi - BT, lcnt, lscan, lcur, adj_lds);
}

// ---- weight staging: pre-swizzled per-lane MFMA B-fragments into LDS ----
// layout: frag[(tbl*8 + kh*4 + nt)*64 + lane]; tbl0 = Wl, tbl1 = Wr
__device__ __forceinline__ void stage_w_lds(half8v* ldsW,
                                            const float* __restrict__ W1,
                                            const float* __restrict__ W2, int tid) {
    for (int f = tid; f < 1024; f += 256) {
        int lane = f & 63, nt = (f >> 6) & 3, kh = (f >> 8) & 1, tbl = f >> 9;
        int m = lane & 15, quad = lane >> 4;
        const float* W = tbl ? W2 : W1;
        half8v frag;
#pragma unroll
        for (int j = 0; j < 8; ++j) {
            int k = kh * 32 + quad * 8 + j;
            frag[j] = (_Float16)W[k * 64 + nt * 16 + m];
        }
        ldsW[f] = frag;
    }
}

// ---- fused gather-mean + dual-weight GEMM (mean@Wl + Self@Wr + b) ------
#define LDSC_STRIDE 72   // halves per row (144 B)
#define LDSC_TBL    1152 // halves per wave tile (16 rows)
__device__ __forceinline__ void gg_dev(
    const int* __restrict__ adj, const int* __restrict__ start, const int* __restrict__ cnt,
    const _Float16* __restrict__ G, const _Float16* __restrict__ S,
    const half8v* __restrict__ ldsW, _Float16* __restrict__ ldsC_w,
    const float* __restrict__ bias,
    _Float16* __restrict__ out, int N, int tile, int do_relu) {
    const int lane = threadIdx.x & 63;
    const int m = lane & 15, quad = lane >> 4;
    const int row = tile * 16 + m;

    half8v accl = {}, acch = {};
    int dg = 0;
    if (row < N) {
        int st = start[row];
        dg     = cnt[row];
        const half8v* G8 = (const half8v*)G;
        int j = 0;
        for (; j + 7 < dg; j += 8) {   // 8 neighbors x 2 chunks in flight
            int n[8];
#pragma unroll
            for (int k = 0; k < 8; ++k) n[k] = adj[st + j + k];
            half8v lv[8], hv[8];
#pragma unroll
            for (int k = 0; k < 8; ++k) {
                const half8v* rp = G8 + (size_t)n[k] * 8 + quad;
                lv[k] = rp[0];
                hv[k] = rp[4];
            }
            accl += ((lv[0] + lv[1]) + (lv[2] + lv[3])) + ((lv[4] + lv[5]) + (lv[6] + lv[7]));
            acch += ((hv[0] + hv[1]) + (hv[2] + hv[3])) + ((hv[4] + hv[5]) + (hv[6] + hv[7]));
        }
        if (j + 3 < dg) {
            int n[4];
#pragma unroll
            for (int k = 0; k < 4; ++k) n[k] = adj[st + j + k];
            half8v lv[4], hv[4];
#pragma unroll
            for (int k = 0; k < 4; ++k) {
                const half8v* rp = G8 + (size_t)n[k] * 8 + quad;
                lv[k] = rp[0];
                hv[k] = rp[4];
            }
            accl += (lv[0] + lv[1]) + (lv[2] + lv[3]);
            acch += (hv[0] + hv[1]) + (hv[2] + hv[3]);
            j += 4;
        }
        for (; j < dg; ++j) {
            const half8v* rp = G8 + (size_t)adj[st + j] * 8 + quad;
            accl += rp[0];
            acch += rp[4];
        }
    }

    f16x8 alo = {}, ahi = {}, slo = {}, shi = {};
    if (row < N) {
        float inv = 1.0f / (float)(dg > 1 ? dg : 1);
#pragma unroll
        for (int k = 0; k < 8; ++k) {
            alo[k] = (_Float16)((float)accl[k] * inv);
            ahi[k] = (_Float16)((float)acch[k] * inv);
        }
        const f16x8* S8 = (const f16x8*)S;
        slo = S8[(size_t)row * 8 + quad];       // self rows: hot gather table for
        shi = S8[(size_t)row * 8 + 4 + quad];   // the other side -> keep cached
    }

#pragma unroll
    for (int nt = 0; nt < 4; ++nt) {
        f16x8 wl_lo = (f16x8)ldsW[(0 * 8 + 0 * 4 + nt) * 64 + lane];
        f16x8 wl_hi = (f16x8)ldsW[(0 * 8 + 1 * 4 + nt) * 64 + lane];
        f16x8 wr_lo = (f16x8)ldsW[(1 * 8 + 0 * 4 + nt) * 64 + lane];
        f16x8 wr_hi = (f16x8)ldsW[(1 * 8 + 1 * 4 + nt) * 64 + lane];
        f32x4 a = {0.f, 0.f, 0.f, 0.f};
        a = MFMA16(alo, wl_lo, a);
        a = MFMA16(ahi, wl_hi, a);
        a = MFMA16(slo, wr_lo, a);
        a = MFMA16(shi, wr_hi, a);
        float bb = bias[nt * 16 + m];
#pragma unroll
        for (int r = 0; r < 4; ++r) {
            float v = a[r] + bb;
            if (do_relu) v = fmaxf(v, 0.f);
            ldsC_w[(quad * 4 + r) * LDSC_STRIDE + nt * 16 + m] = (_Float16)v;
        }
    }

    // coalesced store: lane -> (row = lane>>2, 16B chunk = lane&3), 2 halves
    {
        int rl = lane >> 2, ch = lane & 3;
        int orow = tile * 16 + rl;
        if (orow < N) {
#pragma unroll
            for (int half = 0; half < 2; ++half) {
                int lo = rl * LDSC_STRIDE + ch * 8 + half * 32;
                f16x8 v = *(const f16x8*)&ldsC_w[lo];
                *(f16x8*)&out[(size_t)orow * 64 + ch * 8 + half * 32] = v;
            }
        }
    }
}

// ---- K_C/K_D: fused [gather+dual GEMM], t | p --------------------------
__global__ void __launch_bounds__(256) k_gg(
    const int* __restrict__ adjT, const int* __restrict__ startT, const int* __restrict__ cntT,
    const _Float16* __restrict__ Gt, const _Float16* __restrict__ St,
    const float* __restrict__ Wlt, const float* __restrict__ Wrt, const float* __restrict__ bt,
    _Float16* __restrict__ outT, int NT_,
    const int* __restrict__ adjP, const int* __restrict__ startP, const int* __restrict__ cntP,
    const _Float16* __restrict__ Gp, const _Float16* __restrict__ Sp,
    const float* __restrict__ Wlp, const float* __restrict__ Wrp, const float* __restrict__ bp,
    _Float16* __restrict__ outP, int NP_,
    int tTB, int do_relu) {
    __shared__ half8v ldsW[1024];                            // 16 KiB weight fragments
    __shared__ __align__(16) _Float16 ldsC[4][LDSC_TBL];     // 9 KiB per-wave C tiles
    const int tid = threadIdx.x, wave = tid >> 6;
    if ((int)blockIdx.x < tTB) {
        stage_w_lds(ldsW, Wlt, Wrt, tid);
        __syncthreads();
        int tile = blockIdx.x * 4 + wave;
        if (tile < ((NT_ + 15) >> 4))
            gg_dev(adjT, startT, cntT, Gt, St, ldsW, ldsC[wave], bt, outT, NT_, tile, do_relu);
    } else {
        stage_w_lds(ldsW, Wlp, Wrp, tid);
        __syncthreads();
        int tile = (blockIdx.x - tTB) * 4 + wave;
        if (tile < ((NP_ + 15) >> 4))
            gg_dev(adjP, startP, cntP, Gp, Sp, ldsW, ldsC[wave], bp, outP, NP_, tile, do_relu);
    }
}

// ---- classifier: 8 lanes/edge, v_dot2_f32_f16 --------------------------
__global__ void __launch_bounds__(256) dot_h(const _Float16* __restrict__ p2,
                                             const _Float16* __restrict__ t2,
                                             const int* __restrict__ els,
                                             const int* __restrict__ eld,
                                             float* __restrict__ out, int EL) {
    int tid = blockIdx.x * 256 + threadIdx.x;
    int i = tid >> 3, c = tid & 7;
    if (i < EL) {
        int s = __builtin_nontemporal_load(&els[i]);
        int d = __builtin_nontemporal_load(&eld[i]);
        half8v a = ((const half8v*)p2)[(size_t)s * 8 + c];
        half8v b = ((const half8v*)t2)[(size_t)d * 8 + c];
        float v = 0.f;
#ifdef HAS_FDOT2
        const half2v* ap = (const half2v*)&a;
        const half2v* bp = (const half2v*)&b;
#pragma unroll
        for (int k = 0; k < 4; ++k) v = __builtin_amdgcn_fdot2(ap[k], bp[k], v, false);
#else
#pragma unroll
        for (int k = 0; k < 8; ++k) v += (float)a[k] * (float)b[k];
#endif
        v += __shfl_xor(v, 1, 64);
        v += __shfl_xor(v, 2, 64);
        v += __shfl_xor(v, 4, 64);
        if (c == 0) __builtin_nontemporal_store(v, &out[i]);
    }
}

extern "C" void kernel_launch(void* const* d_in, const int* in_sizes, int n_in,
                              void* d_out, int out_size, void* d_ws, size_t ws_size,
                              hipStream_t stream) {
    const float* x_taxon  = (const float*)d_in[0];
    const float* tlw      = (const float*)d_in[1];
    const float* tlb      = (const float*)d_in[2];
    const float* pemb     = (const float*)d_in[3];
    const float* temb     = (const float*)d_in[4];
    const int*   edge_src = (const int*)d_in[7];
    const int*   edge_dst = (const int*)d_in[8];
    const int*   el_src   = (const int*)d_in[9];
    const int*   el_dst   = (const int*)d_in[10];
    const float* c1pt_wl  = (const float*)d_in[11];
    const float* c1pt_wr  = (const float*)d_in[12];
    const float* c1tp_wl  = (const float*)d_in[13];
    const float* c1tp_wr  = (const float*)d_in[14];
    const float* c2pt_wl  = (const float*)d_in[15];
    const float* c2pt_wr  = (const float*)d_in[16];
    const float* c2tp_wl  = (const float*)d_in[17];
    const float* c2tp_wr  = (const float*)d_in[18];
    const float* c1pt_bl  = (const float*)d_in[19];
    const float* c1tp_bl  = (const float*)d_in[20];
    const float* c2pt_bl  = (const float*)d_in[21];
    const float* c2tp_bl  = (const float*)d_in[22];

    const int NP_ = in_sizes[5];
    const int NT_ = in_sizes[6];
    const int E_  = in_sizes[7];
    const int EL_ = in_sizes[9];
    const int BT  = (NT_ + ST - 1) / ST;   // 391
    const int BP  = (NP_ + SP - 1) / SP;   // 391

    // workspace (gather-then-transform: only raw feature tables live):
    //   XTh [NT]: K_A out (x@tlw+tlb+temb); L1-p gather table, L1-t self; t2 alias
    //   Ph  [NP]: K_A out (f16 pemb);       L1-t gather table, L1-p self; p2 alias
    //   t1  [NT]: L1 out; L2-p gather table, L2-t self
    //   p1  [NP]: L1 out; L2-t gather table, L2-p self
    _Float16* hb  = (_Float16*)d_ws;
    _Float16* XTh = hb;
    _Float16* Ph  = XTh + (size_t)NT_ * H;
    _Float16* t1  = Ph + (size_t)NP_ * H;
    _Float16* p1  = t1 + (size_t)NT_ * H;
    _Float16* t2  = XTh;   // alias: XTh dead after L1
    _Float16* p2  = Ph;    // alias: Ph dead after L1

    unsigned* binT    = (unsigned*)(p1 + (size_t)NP_ * H);   // BT*CAPB
    unsigned* binP    = binT + (size_t)BT * CAPB;            // BP*CAPB
    int*      adj_t   = (int*)(binP + (size_t)BP * CAPB);    // BT*CAPB
    int*      adj_p   = adj_t + (size_t)BT * CAPB;           // BP*CAPB
    int* start_t = adj_p + (size_t)BP * CAPB;  // NT
    int* start_p = start_t + NT_;              // NP
    int* cnt_t   = start_p + NP_;              // NT
    int* cnt_p   = cnt_t + NT_;                // NP
    int* curT    = cnt_p + NP_;                // BMAX
    int* curP    = curT + BMAX;                // BMAX

    (void)hipMemsetAsync(curT, 0, 2 * BMAX * sizeof(int), stream);

    const int nbBin = (E_ + EPB - 1) / EPB;              // 489
    const int XTB   = 512;                               // xt GEMM blocks
    const int CASTB = 256;                               // pemb cast blocks

    // K_A: bin + xt GEMM (XTh = x_taxon@tlw + tlb + temb) + pemb->f16 cast
    k_bin_xt<<<nbBin + XTB + CASTB, 256, 0, stream>>>(
        edge_src, edge_dst, curT, curP, binT, binP, BT, BP, E_, nbBin,
        x_taxon, tlw, tlb, temb, XTh, NT_, XTB, pemb, Ph, NP_, CASTB);

    // K_B: csr-t + csr-p (rows sorted ascending for gather temporal banding)
    k_csr<<<BT + BP, 256, 0, stream>>>(
        binT, binP, curT, curP,
        start_t, cnt_t, adj_t, start_p, cnt_p, adj_p, BT, BP, NT_, NP_);

    const int tTB = (((NT_ + 15) >> 4) + 3) >> 2;
    const int pTB = (((NP_ + 15) >> 4) + 3) >> 2;

    // L1: t1 = relu(mean(Ph[src])@c1pt_wl + XTh@c1pt_wr + c1pt_bl)
    //     p1 = relu(mean(XTh[dst])@c1tp_wl + Ph@c1tp_wr + c1tp_bl)
    k_gg<<<tTB + pTB, 256, 0, stream>>>(
        adj_t, start_t, cnt_t, Ph, XTh, c1pt_wl, c1pt_wr, c1pt_bl, t1, NT_,
        adj_p, start_p, cnt_p, XTh, Ph, c1tp_wl, c1tp_wr, c1tp_bl, p1, NP_,
        tTB, 1);

    // L2: t2 = mean(p1[src])@c2pt_wl + t1@c2pt_wr + c2pt_bl
    //     p2 = mean(t1[dst])@c2tp_wl + p1@c2tp_wr + c2tp_bl
    k_gg<<<tTB + pTB, 256, 0, stream>>>(
        adj_t, start_t, cnt_t, p1, t1, c2pt_wl, c2pt_wr, c2pt_bl, t2, NT_,
        adj_p, start_p, cnt_p, t1, p1, c2tp_wl, c2tp_wr, c2tp_bl, p2, NP_,
        tTB, 0);

    // classifier
    dot_h<<<(EL_ * 8 + 255) / 256, 256, 0, stream>>>(p2, t2, el_src, el_dst,
                                                     (float*)d_out, EL_);
}

// Round 12
// 471.749 us; speedup vs baseline: 1.0646x; 1.0646x over previous
//
#include <hip/hip_runtime.h>

#define H 64
#define EPB 4096        // edges per bin block (489 blocks)
#define BMAX 400        // >= bucket count (391)
#define ST 256          // taxon rows per bucket
#define SP 512          // palmprint rows per bucket
#define LSHT 18         // t-entry: (dst&255)<<18 | src
#define LSHP 17         // p-entry: (src&511)<<17 | dst
#define CAPB 5632       // bucket capacity (mean 5120 + 7 sigma); %4==0

typedef _Float16 half2v __attribute__((ext_vector_type(2)));
typedef _Float16 half8v __attribute__((ext_vector_type(8)));
typedef _Float16 f16x8  __attribute__((ext_vector_type(8)));
typedef float    f32x4  __attribute__((ext_vector_type(4)));
typedef int      i32x4  __attribute__((ext_vector_type(4)));

#if defined(__has_builtin)
#if __has_builtin(__builtin_amdgcn_fdot2)
#define HAS_FDOT2 1
#endif
#endif

#define MFMA16(a, b, c) __builtin_amdgcn_mfma_f32_16x16x32_f16(a, b, c, 0, 0, 0)

// ---- MFMA xt device body: C = A(f32)@W + bias + addend(f32), f16 out ----
__device__ __forceinline__ void mfma_xt_dev(const float* __restrict__ A,
                                            const float* __restrict__ W,
                                            const float* __restrict__ bias,
                                            const float* __restrict__ addend,
                                            _Float16* __restrict__ C,
                                            int N, int wid, int nwaves) {
    const int lane = threadIdx.x & 63;
    const int m = lane & 15, quad = lane >> 4;
    const int nTiles = (N + 15) >> 4;

    f16x8 wf[2][4];
#pragma unroll
    for (int kh = 0; kh < 2; ++kh)
#pragma unroll
        for (int nt = 0; nt < 4; ++nt) {
            f16x8 a;
#pragma unroll
            for (int j = 0; j < 8; ++j) {
                int k = kh * 32 + quad * 8 + j;
                a[j] = (_Float16)W[k * 64 + nt * 16 + m];
            }
            wf[kh][nt] = a;
        }
    float bv[4];
#pragma unroll
    for (int nt = 0; nt < 4; ++nt) bv[nt] = bias[nt * 16 + m];

    for (int t = wid; t < nTiles; t += nwaves) {
        int row = t * 16 + m;
        f16x8 alo = {}, ahi = {};
        if (row < N) {
            const f32x4* p = (const f32x4*)(A + (size_t)row * 64);
            f32x4 x0 = __builtin_nontemporal_load(p + quad * 2);
            f32x4 x1 = __builtin_nontemporal_load(p + quad * 2 + 1);
            f32x4 x2 = __builtin_nontemporal_load(p + 8 + quad * 2);
            f32x4 x3 = __builtin_nontemporal_load(p + 8 + quad * 2 + 1);
            alo[0] = (_Float16)x0[0]; alo[1] = (_Float16)x0[1];
            alo[2] = (_Float16)x0[2]; alo[3] = (_Float16)x0[3];
            alo[4] = (_Float16)x1[0]; alo[5] = (_Float16)x1[1];
            alo[6] = (_Float16)x1[2]; alo[7] = (_Float16)x1[3];
            ahi[0] = (_Float16)x2[0]; ahi[1] = (_Float16)x2[1];
            ahi[2] = (_Float16)x2[2]; ahi[3] = (_Float16)x2[3];
            ahi[4] = (_Float16)x3[0]; ahi[5] = (_Float16)x3[1];
            ahi[6] = (_Float16)x3[2]; ahi[7] = (_Float16)x3[3];
        }
#pragma unroll
        for (int nt = 0; nt < 4; ++nt) {
            f32x4 a1 = {0.f, 0.f, 0.f, 0.f};
            a1 = MFMA16(alo, wf[0][nt], a1);
            a1 = MFMA16(ahi, wf[1][nt], a1);
#pragma unroll
            for (int r = 0; r < 4; ++r) {
                int orow = t * 16 + quad * 4 + r;
                if (orow < N) {
                    float ad = __builtin_nontemporal_load(
                        &addend[(size_t)orow * 64 + nt * 16 + m]);
                    C[(size_t)orow * 64 + nt * 16 + m] = (_Float16)(a1[r] + bv[nt] + ad);
                }
            }
        }
    }
}

// in-place inclusive scan over sc[0..511] (counts pre-loaded), 256 threads
__device__ __forceinline__ void block_scan512(int* sc, int tid) {
    for (int off = 1; off < 512; off <<= 1) {
        int i0 = tid, i1 = tid + 256;
        int v0 = (i0 >= off) ? sc[i0 - off] : 0;
        int v1 = (i1 >= off) ? sc[i1 - off] : 0;
        __syncthreads();
        sc[i0] += v0;
        sc[i1] += v1;
        __syncthreads();
    }
}

// ---- K_A: fused [bin (LDS sort-then-stream) | xt GEMM | pemb cast] -----
__global__ void __launch_bounds__(256) k_bin_xt(
    const int* __restrict__ src, const int* __restrict__ dst,
    int* __restrict__ curT, int* __restrict__ curP,
    unsigned* __restrict__ binT, unsigned* __restrict__ binP,
    int BT, int BP, int E, int nbBin,
    const float* __restrict__ A, const float* __restrict__ W,
    const float* __restrict__ bias, const float* __restrict__ addend,
    _Float16* __restrict__ C, int NT_, int xtBlocks,
    const float* __restrict__ pembIn, _Float16* __restrict__ PhOut,
    int NP_, int castBlocks) {
    __shared__ int cT[BMAX], cP[BMAX], oT[BMAX], oP[BMAX], cur[BMAX];
    __shared__ int sc[512];
    __shared__ unsigned stage[EPB];
    int tid = threadIdx.x;
    if ((int)blockIdx.x >= nbBin + xtBlocks) {
        // pemb f32 -> f16 cast (read-once stream)
        int cb = blockIdx.x - nbBin - xtBlocks;
        int idx = cb * 256 + tid, stride = castBlocks * 256;
        int total = NP_ * 8;
        for (int i = idx; i < total; i += stride) {
            const f32x4* p = (const f32x4*)(pembIn + (size_t)i * 8);
            f32x4 x0 = __builtin_nontemporal_load(p);
            f32x4 x1 = __builtin_nontemporal_load(p + 1);
            f16x8 o;
            o[0] = (_Float16)x0[0]; o[1] = (_Float16)x0[1];
            o[2] = (_Float16)x0[2]; o[3] = (_Float16)x0[3];
            o[4] = (_Float16)x1[0]; o[5] = (_Float16)x1[1];
            o[6] = (_Float16)x1[2]; o[7] = (_Float16)x1[3];
            *(f16x8*)&PhOut[(size_t)i * 8] = o;
        }
        return;
    }
    if ((int)blockIdx.x >= nbBin) {
        int xb = blockIdx.x - nbBin;
        mfma_xt_dev(A, W, bias, addend, C, NT_, xb * 4 + (tid >> 6), xtBlocks * 4);
        return;
    }
    const int wave = tid >> 6, lane = tid & 63;
    for (int i = tid; i < BMAX; i += 256) { cT[i] = 0; cP[i] = 0; }
    __syncthreads();
    int e0 = blockIdx.x * EPB;
    int ls[EPB / 256], ld[EPB / 256];
#pragma unroll
    for (int k = 0; k < EPB / 256; ++k) {
        int i = e0 + k * 256 + tid;
        if (i < E) {
            ls[k] = __builtin_nontemporal_load(&src[i]);
            ld[k] = __builtin_nontemporal_load(&dst[i]);
            atomicAdd(&cT[ld[k] >> 8], 1);
            atomicAdd(&cP[ls[k] >> 9], 1);
        }
    }
    __syncthreads();
    // grab global chunks
    for (int b = tid; b < BT; b += 256) { int c = cT[b]; oT[b] = c ? atomicAdd(&curT[b], c) : 0; }
    for (int b = tid; b < BP; b += 256) { int c = cP[b]; oP[b] = c ? atomicAdd(&curP[b], c) : 0; }
    // ---- T side: scan, scatter to LDS, stream out ----
    sc[tid]       = (tid < BT) ? cT[tid] : 0;
    sc[tid + 256] = (tid + 256 < BT) ? cT[tid + 256] : 0;
    __syncthreads();
    block_scan512(sc, tid);
    for (int b = tid; b < BT; b += 256) cur[b] = sc[b] - cT[b];
    __syncthreads();
#pragma unroll
    for (int k = 0; k < EPB / 256; ++k) {
        int i = e0 + k * 256 + tid;
        if (i < E) {
            int bt = ld[k] >> 8;
            int pos = atomicAdd(&cur[bt], 1);
            stage[pos] = ((unsigned)(ld[k] & 255) << LSHT) | (unsigned)ls[k];
        }
    }
    __syncthreads();
    for (int b = wave; b < BT; b += 4) {
        int cnt = cT[b], so = sc[b] - cnt, go = oT[b];
        for (int i = lane; i < cnt; i += 64) {
            int pos = go + i;
            if (pos < CAPB) binT[(size_t)b * CAPB + pos] = stage[so + i];
        }
    }
    __syncthreads();
    // ---- P side ----
    sc[tid]       = (tid < BP) ? cP[tid] : 0;
    sc[tid + 256] = (tid + 256 < BP) ? cP[tid + 256] : 0;
    __syncthreads();
    block_scan512(sc, tid);
    for (int b = tid; b < BP; b += 256) cur[b] = sc[b] - cP[b];
    __syncthreads();
#pragma unroll
    for (int k = 0; k < EPB / 256; ++k) {
        int i = e0 + k * 256 + tid;
        if (i < E) {
            int bp = ls[k] >> 9;
            int pos = atomicAdd(&cur[bp], 1);
            stage[pos] = ((unsigned)(ls[k] & 511) << LSHP) | (unsigned)ld[k];
        }
    }
    __syncthreads();
    for (int b = wave; b < BP; b += 4) {
        int cnt = cP[b], so = sc[b] - cnt, go = oP[b];
        for (int i = lane; i < cnt; i += 64) {
            int pos = go + i;
            if (pos < CAPB) binP[(size_t)b * CAPB + pos] = stage[so + i];
        }
    }
}

// ---- CSR per-bucket device body: scatter into LDS, stream out int4 -----
__device__ __forceinline__ void csr_dev(const unsigned* __restrict__ binned,
                                        const int* __restrict__ cur,
                                        int* __restrict__ start_g, int* __restrict__ cnt_g,
                                        int* __restrict__ adj,
                                        int S, int lshift, int N, int b,
                                        int* lcnt, int* lscan, int* lcur, int* adj_lds) {
    int tid = threadIdx.x;
    int base = b * CAPB;
    int n = cur[b]; if (n > CAPB) n = CAPB;
    int rowlo = b * S;
    unsigned nbmask = (1u << lshift) - 1u;

    for (int i = tid; i < S; i += 256) lcnt[i] = 0;
    __syncthreads();
    for (int i = tid; i < n; i += 256)
        atomicAdd(&lcnt[binned[base + i] >> lshift], 1);
    __syncthreads();
    for (int i = tid; i < S; i += 256) lscan[i] = lcnt[i];
    __syncthreads();
    for (int off = 1; off < S; off <<= 1) {
        int i0 = tid, i1 = tid + 256;
        int v0 = (i0 >= off) ? lscan[i0 - off] : 0;
        int v1 = (S > 256 && i1 >= off) ? lscan[i1 - off] : 0;
        __syncthreads();
        if (i0 < S) lscan[i0] += v0;
        if (S > 256 && i1 < S) lscan[i1] += v1;
        __syncthreads();
    }
    for (int r = tid; r < S; r += 256) {
        int ex = lscan[r] - lcnt[r];
        lcur[r] = ex;
        int row = rowlo + r;
        if (row < N) {
            start_g[row] = base + ex;
            cnt_g[row]   = lcnt[r];
        }
    }
    __syncthreads();
    for (int i = tid; i < n; i += 256) {
        unsigned e = binned[base + i];
        int r = e >> lshift;
        int pos = atomicAdd(&lcur[r], 1);
        adj_lds[pos] = (int)(e & nbmask);
    }
    __syncthreads();
    int n4 = n & ~3;
    for (int i = tid * 4; i < n4; i += 1024)
        *(int4*)&adj[base + i] = *(const int4*)&adj_lds[i];
    for (int i = n4 + tid; i < n; i += 256)
        adj[base + i] = adj_lds[i];
}

// ---- K_B: [csr-t | csr-p] ----------------------------------------------
__global__ void __launch_bounds__(256) k_csr(
    const unsigned* __restrict__ binT, const unsigned* __restrict__ binP,
    const int* __restrict__ curT, const int* __restrict__ curP,
    int* __restrict__ start_t, int* __restrict__ cnt_t, int* __restrict__ adj_t,
    int* __restrict__ start_p, int* __restrict__ cnt_p, int* __restrict__ adj_p,
    int BT, int BP, int NT_, int NP_) {
    __shared__ int lcnt[512], lscan[512], lcur[512];
    __shared__ int adj_lds[CAPB];
    int bi = blockIdx.x;
    if (bi < BT)
        csr_dev(binT, curT, start_t, cnt_t, adj_t, ST, LSHT, NT_, bi, lcnt, lscan, lcur, adj_lds);
    else
        csr_dev(binP, curP, start_p, cnt_p, adj_p, SP, LSHP, NP_, bi - BT, lcnt, lscan, lcur, adj_lds);
}

// ---- weight staging: pre-swizzled per-lane MFMA B-fragments into LDS ----
// layout: frag[(tbl*8 + kh*4 + nt)*64 + lane]; tbl0 = Wl, tbl1 = Wr
__device__ __forceinline__ void stage_w_lds(half8v* ldsW,
                                            const float* __restrict__ W1,
                                            const float* __restrict__ W2, int tid) {
    for (int f = tid; f < 1024; f += 256) {
        int lane = f & 63, nt = (f >> 6) & 3, kh = (f >> 8) & 1, tbl = f >> 9;
        int m = lane & 15, quad = lane >> 4;
        const float* W = tbl ? W2 : W1;
        half8v frag;
#pragma unroll
        for (int j = 0; j < 8; ++j) {
            int k = kh * 32 + quad * 8 + j;
            frag[j] = (_Float16)W[k * 64 + nt * 16 + m];
        }
        ldsW[f] = frag;
    }
}

// ---- fused gather-mean + dual-weight GEMM (mean@Wl + Self@Wr + b) ------
#define LDSC_STRIDE 72   // halves per row (144 B)
#define LDSC_TBL    1152 // halves per wave tile (16 rows)
__device__ __forceinline__ void gg_dev(
    const int* __restrict__ adj, const int* __restrict__ start, const int* __restrict__ cnt,
    const _Float16* __restrict__ G, const _Float16* __restrict__ S,
    const half8v* __restrict__ ldsW, _Float16* __restrict__ ldsC_w,
    const float* __restrict__ bias,
    _Float16* __restrict__ out, int N, int tile, int do_relu) {
    const int lane = threadIdx.x & 63;
    const int m = lane & 15, quad = lane >> 4;
    const int row = tile * 16 + m;

    half8v accl = {}, acch = {};
    int dg = 0;
    if (row < N) {
        int st = start[row];
        dg     = cnt[row];
        const half8v* G8 = (const half8v*)G;
        int j = 0;
        for (; j + 7 < dg; j += 8) {   // 8 neighbors x 2 chunks in flight
            int n[8];
#pragma unroll
            for (int k = 0; k < 8; ++k) n[k] = adj[st + j + k];
            half8v lv[8], hv[8];
#pragma unroll
            for (int k = 0; k < 8; ++k) {
                const half8v* rp = G8 + (size_t)n[k] * 8 + quad;
                lv[k] = rp[0];
                hv[k] = rp[4];
            }
            accl += ((lv[0] + lv[1]) + (lv[2] + lv[3])) + ((lv[4] + lv[5]) + (lv[6] + lv[7]));
            acch += ((hv[0] + hv[1]) + (hv[2] + hv[3])) + ((hv[4] + hv[5]) + (hv[6] + hv[7]));
        }
        if (j + 3 < dg) {
            int n[4];
#pragma unroll
            for (int k = 0; k < 4; ++k) n[k] = adj[st + j + k];
            half8v lv[4], hv[4];
#pragma unroll
            for (int k = 0; k < 4; ++k) {
                const half8v* rp = G8 + (size_t)n[k] * 8 + quad;
                lv[k] = rp[0];
                hv[k] = rp[4];
            }
            accl += (lv[0] + lv[1]) + (lv[2] + lv[3]);
            acch += (hv[0] + hv[1]) + (hv[2] + hv[3]);
            j += 4;
        }
        for (; j < dg; ++j) {
            const half8v* rp = G8 + (size_t)adj[st + j] * 8 + quad;
            accl += rp[0];
            acch += rp[4];
        }
    }

    f16x8 alo = {}, ahi = {}, slo = {}, shi = {};
    if (row < N) {
        float inv = 1.0f / (float)(dg > 1 ? dg : 1);
#pragma unroll
        for (int k = 0; k < 8; ++k) {
            alo[k] = (_Float16)((float)accl[k] * inv);
            ahi[k] = (_Float16)((float)acch[k] * inv);
        }
        const f16x8* S8 = (const f16x8*)S;
        slo = S8[(size_t)row * 8 + quad];       // self rows: hot gather table for
        shi = S8[(size_t)row * 8 + 4 + quad];   // the other side -> keep cached
    }

#pragma unroll
    for (int nt = 0; nt < 4; ++nt) {
        f16x8 wl_lo = (f16x8)ldsW[(0 * 8 + 0 * 4 + nt) * 64 + lane];
        f16x8 wl_hi = (f16x8)ldsW[(0 * 8 + 1 * 4 + nt) * 64 + lane];
        f16x8 wr_lo = (f16x8)ldsW[(1 * 8 + 0 * 4 + nt) * 64 + lane];
        f16x8 wr_hi = (f16x8)ldsW[(1 * 8 + 1 * 4 + nt) * 64 + lane];
        f32x4 a = {0.f, 0.f, 0.f, 0.f};
        a = MFMA16(alo, wl_lo, a);
        a = MFMA16(ahi, wl_hi, a);
        a = MFMA16(slo, wr_lo, a);
        a = MFMA16(shi, wr_hi, a);
        float bb = bias[nt * 16 + m];
#pragma unroll
        for (int r = 0; r < 4; ++r) {
            float v = a[r] + bb;
            if (do_relu) v = fmaxf(v, 0.f);
            ldsC_w[(quad * 4 + r) * LDSC_STRIDE + nt * 16 + m] = (_Float16)v;
        }
    }

    // coalesced store: lane -> (row = lane>>2, 16B chunk = lane&3), 2 halves
    {
        int rl = lane >> 2, ch = lane & 3;
        int orow = tile * 16 + rl;
        if (orow < N) {
#pragma unroll
            for (int half = 0; half < 2; ++half) {
                int lo = rl * LDSC_STRIDE + ch * 8 + half * 32;
                f16x8 v = *(const f16x8*)&ldsC_w[lo];
                *(f16x8*)&out[(size_t)orow * 64 + ch * 8 + half * 32] = v;
            }
        }
    }
}

// ---- K_C..K_F: single-sided fused [gather+dual GEMM] -------------------
// (t and p sides as separate dispatches: per-phase rocprof visibility +
//  full cache-phase separation between the two gather tables)
__global__ void __launch_bounds__(256) k_gg1(
    const int* __restrict__ adj, const int* __restrict__ start, const int* __restrict__ cnt,
    const _Float16* __restrict__ G, const _Float16* __restrict__ S,
    const float* __restrict__ Wl, const float* __restrict__ Wr, const float* __restrict__ b,
    _Float16* __restrict__ out, int N, int do_relu) {
    __shared__ half8v ldsW[1024];                            // 16 KiB weight fragments
    __shared__ __align__(16) _Float16 ldsC[4][LDSC_TBL];     // 9 KiB per-wave C tiles
    const int tid = threadIdx.x, wave = tid >> 6;
    stage_w_lds(ldsW, Wl, Wr, tid);
    __syncthreads();
    int tile = blockIdx.x * 4 + wave;
    if (tile < ((N + 15) >> 4))
        gg_dev(adj, start, cnt, G, S, ldsW, ldsC[wave], b, out, N, tile, do_relu);
}

// ---- classifier: 8 lanes/edge, v_dot2_f32_f16 --------------------------
__global__ void __launch_bounds__(256) dot_h(const _Float16* __restrict__ p2,
                                             const _Float16* __restrict__ t2,
                                             const int* __restrict__ els,
                                             const int* __restrict__ eld,
                                             float* __restrict__ out, int EL) {
    int tid = blockIdx.x * 256 + threadIdx.x;
    int i = tid >> 3, c = tid & 7;
    if (i < EL) {
        int s = __builtin_nontemporal_load(&els[i]);
        int d = __builtin_nontemporal_load(&eld[i]);
        half8v a = ((const half8v*)p2)[(size_t)s * 8 + c];
        half8v b = ((const half8v*)t2)[(size_t)d * 8 + c];
        float v = 0.f;
#ifdef HAS_FDOT2
        const half2v* ap = (const half2v*)&a;
        const half2v* bp = (const half2v*)&b;
#pragma unroll
        for (int k = 0; k < 4; ++k) v = __builtin_amdgcn_fdot2(ap[k], bp[k], v, false);
#else
#pragma unroll
        for (int k = 0; k < 8; ++k) v += (float)a[k] * (float)b[k];
#endif
        v += __shfl_xor(v, 1, 64);
        v += __shfl_xor(v, 2, 64);
        v += __shfl_xor(v, 4, 64);
        if (c == 0) __builtin_nontemporal_store(v, &out[i]);
    }
}

extern "C" void kernel_launch(void* const* d_in, const int* in_sizes, int n_in,
                              void* d_out, int out_size, void* d_ws, size_t ws_size,
                              hipStream_t stream) {
    const float* x_taxon  = (const float*)d_in[0];
    const float* tlw      = (const float*)d_in[1];
    const float* tlb      = (const float*)d_in[2];
    const float* pemb     = (const float*)d_in[3];
    const float* temb     = (const float*)d_in[4];
    const int*   edge_src = (const int*)d_in[7];
    const int*   edge_dst = (const int*)d_in[8];
    const int*   el_src   = (const int*)d_in[9];
    const int*   el_dst   = (const int*)d_in[10];
    const float* c1pt_wl  = (const float*)d_in[11];
    const float* c1pt_wr  = (const float*)d_in[12];
    const float* c1tp_wl  = (const float*)d_in[13];
    const float* c1tp_wr  = (const float*)d_in[14];
    const float* c2pt_wl  = (const float*)d_in[15];
    const float* c2pt_wr  = (const float*)d_in[16];
    const float* c2tp_wl  = (const float*)d_in[17];
    const float* c2tp_wr  = (const float*)d_in[18];
    const float* c1pt_bl  = (const float*)d_in[19];
    const float* c1tp_bl  = (const float*)d_in[20];
    const float* c2pt_bl  = (const float*)d_in[21];
    const float* c2tp_bl  = (const float*)d_in[22];

    const int NP_ = in_sizes[5];
    const int NT_ = in_sizes[6];
    const int E_  = in_sizes[7];
    const int EL_ = in_sizes[9];
    const int BT  = (NT_ + ST - 1) / ST;   // 391
    const int BP  = (NP_ + SP - 1) / SP;   // 391

    // workspace (gather-then-transform: only raw feature tables live):
    //   XTh [NT]: K_A out (x@tlw+tlb+temb); L1-p gather table, L1-t self; t2 alias
    //   Ph  [NP]: K_A out (f16 pemb);       L1-t gather table, L1-p self; p2 alias
    //   t1  [NT]: L1 out; L2-p gather table, L2-t self
    //   p1  [NP]: L1 out; L2-t gather table, L2-p self
    _Float16* hb  = (_Float16*)d_ws;
    _Float16* XTh = hb;
    _Float16* Ph  = XTh + (size_t)NT_ * H;
    _Float16* t1  = Ph + (size_t)NP_ * H;
    _Float16* p1  = t1 + (size_t)NT_ * H;
    _Float16* t2  = XTh;   // alias: XTh dead after L1
    _Float16* p2  = Ph;    // alias: Ph dead after L1

    unsigned* binT    = (unsigned*)(p1 + (size_t)NP_ * H);   // BT*CAPB
    unsigned* binP    = binT + (size_t)BT * CAPB;            // BP*CAPB
    int*      adj_t   = (int*)(binP + (size_t)BP * CAPB);    // BT*CAPB
    int*      adj_p   = adj_t + (size_t)BT * CAPB;           // BP*CAPB
    int* start_t = adj_p + (size_t)BP * CAPB;  // NT
    int* start_p = start_t + NT_;              // NP
    int* cnt_t   = start_p + NP_;              // NT
    int* cnt_p   = cnt_t + NT_;                // NP
    int* curT    = cnt_p + NP_;                // BMAX
    int* curP    = curT + BMAX;                // BMAX

    (void)hipMemsetAsync(curT, 0, 2 * BMAX * sizeof(int), stream);

    const int nbBin = (E_ + EPB - 1) / EPB;              // 489
    const int XTB   = 512;                               // xt GEMM blocks
    const int CASTB = 256;                               // pemb cast blocks

    // K_A: bin + xt GEMM (XTh = x_taxon@tlw + tlb + temb) + pemb->f16 cast
    k_bin_xt<<<nbBin + XTB + CASTB, 256, 0, stream>>>(
        edge_src, edge_dst, curT, curP, binT, binP, BT, BP, E_, nbBin,
        x_taxon, tlw, tlb, temb, XTh, NT_, XTB, pemb, Ph, NP_, CASTB);

    // K_B: csr-t + csr-p
    k_csr<<<BT + BP, 256, 0, stream>>>(
        binT, binP, curT, curP,
        start_t, cnt_t, adj_t, start_p, cnt_p, adj_p, BT, BP, NT_, NP_);

    const int tTB = (((NT_ + 15) >> 4) + 3) >> 2;
    const int pTB = (((NP_ + 15) >> 4) + 3) >> 2;

    // L1-t: t1 = relu(mean(Ph[src])@c1pt_wl + XTh@c1pt_wr + c1pt_bl)
    k_gg1<<<tTB, 256, 0, stream>>>(
        adj_t, start_t, cnt_t, Ph, XTh, c1pt_wl, c1pt_wr, c1pt_bl, t1, NT_, 1);
    // L1-p: p1 = relu(mean(XTh[dst])@c1tp_wl + Ph@c1tp_wr + c1tp_bl)
    k_gg1<<<pTB, 256, 0, stream>>>(
        adj_p, start_p, cnt_p, XTh, Ph, c1tp_wl, c1tp_wr, c1tp_bl, p1, NP_, 1);

    // L2-t: t2 = mean(p1[src])@c2pt_wl + t1@c2pt_wr + c2pt_bl
    k_gg1<<<tTB, 256, 0, stream>>>(
        adj_t, start_t, cnt_t, p1, t1, c2pt_wl, c2pt_wr, c2pt_bl, t2, NT_, 0);
    // L2-p: p2 = mean(t1[dst])@c2tp_wl + p1@c2tp_wr + c2tp_bl
    k_gg1<<<pTB, 256, 0, stream>>>(
        adj_p, start_p, cnt_p, t1, p1, c2tp_wl, c2tp_wr, c2tp_bl, p2, NP_, 0);

    // classifier
    dot_h<<<(EL_ * 8 + 255) / 256, 256, 0, stream>>>(p2, t2, el_src, el_dst,
                                                     (float*)d_out, EL_);
}

// Round 14
// 451.078 us; speedup vs baseline: 1.1134x; 1.0458x over previous
//
#include <hip/hip_runtime.h>

#define H 64
#define EPB 4096        // edges per bin block (489 blocks)
#define BMAX 400        // >= bucket count (391)
#define ST 256          // taxon rows per bucket
#define SP 512          // palmprint rows per bucket
#define LSHT 18         // t-entry: (dst&255)<<18 | src
#define LSHP 17         // p-entry: (src&511)<<17 | dst
#define CAPB 5632       // bucket capacity (mean 5120 + 7 sigma); %4==0
#define CURST 16        // cur counter stride (64B: one counter per cache line)

typedef _Float16 half2v __attribute__((ext_vector_type(2)));
typedef _Float16 half8v __attribute__((ext_vector_type(8)));
typedef _Float16 f16x8  __attribute__((ext_vector_type(8)));
typedef float    f32x4  __attribute__((ext_vector_type(4)));
typedef int      i32x4  __attribute__((ext_vector_type(4)));

#if defined(__has_builtin)
#if __has_builtin(__builtin_amdgcn_fdot2)
#define HAS_FDOT2 1
#endif
#endif

#define MFMA16(a, b, c) __builtin_amdgcn_mfma_f32_16x16x32_f16(a, b, c, 0, 0, 0)

// ---- MFMA xt device body: C = A(f32)@W + bias + addend(f32), f16 out ----
__device__ __forceinline__ void mfma_xt_dev(const float* __restrict__ A,
                                            const float* __restrict__ W,
                                            const float* __restrict__ bias,
                                            const float* __restrict__ addend,
                                            _Float16* __restrict__ C,
                                            int N, int wid, int nwaves) {
    const int lane = threadIdx.x & 63;
    const int m = lane & 15, quad = lane >> 4;
    const int nTiles = (N + 15) >> 4;

    f16x8 wf[2][4];
#pragma unroll
    for (int kh = 0; kh < 2; ++kh)
#pragma unroll
        for (int nt = 0; nt < 4; ++nt) {
            f16x8 a;
#pragma unroll
            for (int j = 0; j < 8; ++j) {
                int k = kh * 32 + quad * 8 + j;
                a[j] = (_Float16)W[k * 64 + nt * 16 + m];
            }
            wf[kh][nt] = a;
        }
    float bv[4];
#pragma unroll
    for (int nt = 0; nt < 4; ++nt) bv[nt] = bias[nt * 16 + m];

    for (int t = wid; t < nTiles; t += nwaves) {
        int row = t * 16 + m;
        f16x8 alo = {}, ahi = {};
        if (row < N) {
            const f32x4* p = (const f32x4*)(A + (size_t)row * 64);
            f32x4 x0 = __builtin_nontemporal_load(p + quad * 2);
            f32x4 x1 = __builtin_nontemporal_load(p + quad * 2 + 1);
            f32x4 x2 = __builtin_nontemporal_load(p + 8 + quad * 2);
            f32x4 x3 = __builtin_nontemporal_load(p + 8 + quad * 2 + 1);
            alo[0] = (_Float16)x0[0]; alo[1] = (_Float16)x0[1];
            alo[2] = (_Float16)x0[2]; alo[3] = (_Float16)x0[3];
            alo[4] = (_Float16)x1[0]; alo[5] = (_Float16)x1[1];
            alo[6] = (_Float16)x1[2]; alo[7] = (_Float16)x1[3];
            ahi[0] = (_Float16)x2[0]; ahi[1] = (_Float16)x2[1];
            ahi[2] = (_Float16)x2[2]; ahi[3] = (_Float16)x2[3];
            ahi[4] = (_Float16)x3[0]; ahi[5] = (_Float16)x3[1];
            ahi[6] = (_Float16)x3[2]; ahi[7] = (_Float16)x3[3];
        }
#pragma unroll
        for (int nt = 0; nt < 4; ++nt) {
            f32x4 a1 = {0.f, 0.f, 0.f, 0.f};
            a1 = MFMA16(alo, wf[0][nt], a1);
            a1 = MFMA16(ahi, wf[1][nt], a1);
#pragma unroll
            for (int r = 0; r < 4; ++r) {
                int orow = t * 16 + quad * 4 + r;
                if (orow < N) {
                    float ad = __builtin_nontemporal_load(
                        &addend[(size_t)orow * 64 + nt * 16 + m]);
                    C[(size_t)orow * 64 + nt * 16 + m] = (_Float16)(a1[r] + bv[nt] + ad);
                }
            }
        }
    }
}

// in-place inclusive scan over sc[0..511] (counts pre-loaded), 256 threads
__device__ __forceinline__ void block_scan512(int* sc, int tid) {
    for (int off = 1; off < 512; off <<= 1) {
        int i0 = tid, i1 = tid + 256;
        int v0 = (i0 >= off) ? sc[i0 - off] : 0;
        int v1 = (i1 >= off) ? sc[i1 - off] : 0;
        __syncthreads();
        sc[i0] += v0;
        sc[i1] += v1;
        __syncthreads();
    }
}

// ---- K_A: fused [bin (LDS sort-then-stream) | xt GEMM | pemb cast] -----
// curT/curP are line-padded (CURST) and traversed block-rotated to kill
// cross-XCD atomic contention on the chunk-grab.
__global__ void __launch_bounds__(256) k_bin_xt(
    const int* __restrict__ src, const int* __restrict__ dst,
    int* __restrict__ curT, int* __restrict__ curP,
    unsigned* __restrict__ binT, unsigned* __restrict__ binP,
    int BT, int BP, int E, int nbBin,
    const float* __restrict__ A, const float* __restrict__ W,
    const float* __restrict__ bias, const float* __restrict__ addend,
    _Float16* __restrict__ C, int NT_, int xtBlocks,
    const float* __restrict__ pembIn, _Float16* __restrict__ PhOut,
    int NP_, int castBlocks) {
    __shared__ int cT[BMAX], cP[BMAX], oT[BMAX], oP[BMAX], cur[BMAX];
    __shared__ int sc[512];
    __shared__ unsigned stage[EPB];
    int tid = threadIdx.x;
    if ((int)blockIdx.x >= nbBin + xtBlocks) {
        // pemb f32 -> f16 cast (read-once stream)
        int cb = blockIdx.x - nbBin - xtBlocks;
        int idx = cb * 256 + tid, stride = castBlocks * 256;
        int total = NP_ * 8;
        for (int i = idx; i < total; i += stride) {
            const f32x4* p = (const f32x4*)(pembIn + (size_t)i * 8);
            f32x4 x0 = __builtin_nontemporal_load(p);
            f32x4 x1 = __builtin_nontemporal_load(p + 1);
            f16x8 o;
            o[0] = (_Float16)x0[0]; o[1] = (_Float16)x0[1];
            o[2] = (_Float16)x0[2]; o[3] = (_Float16)x0[3];
            o[4] = (_Float16)x1[0]; o[5] = (_Float16)x1[1];
            o[6] = (_Float16)x1[2]; o[7] = (_Float16)x1[3];
            *(f16x8*)&PhOut[(size_t)i * 8] = o;
        }
        return;
    }
    if ((int)blockIdx.x >= nbBin) {
        int xb = blockIdx.x - nbBin;
        mfma_xt_dev(A, W, bias, addend, C, NT_, xb * 4 + (tid >> 6), xtBlocks * 4);
        return;
    }
    const int wave = tid >> 6, lane = tid & 63;
    for (int i = tid; i < BMAX; i += 256) { cT[i] = 0; cP[i] = 0; }
    __syncthreads();
    int e0 = blockIdx.x * EPB;
    int ls[EPB / 256], ld[EPB / 256];
#pragma unroll
    for (int k = 0; k < EPB / 256; ++k) {
        int i = e0 + k * 256 + tid;
        if (i < E) {
            ls[k] = __builtin_nontemporal_load(&src[i]);
            ld[k] = __builtin_nontemporal_load(&dst[i]);
            atomicAdd(&cT[ld[k] >> 8], 1);
            atomicAdd(&cP[ls[k] >> 9], 1);
        }
    }
    __syncthreads();
    // grab global chunks (padded counters + per-block rotated order)
    {
        int rotT = (int)((blockIdx.x * 53u) % (unsigned)BT);
        for (int b0 = tid; b0 < BT; b0 += 256) {
            int b = b0 + rotT; if (b >= BT) b -= BT;
            int c = cT[b]; oT[b] = c ? atomicAdd(&curT[b * CURST], c) : 0;
        }
        int rotP = (int)((blockIdx.x * 29u) % (unsigned)BP);
        for (int b0 = tid; b0 < BP; b0 += 256) {
            int b = b0 + rotP; if (b >= BP) b -= BP;
            int c = cP[b]; oP[b] = c ? atomicAdd(&curP[b * CURST], c) : 0;
        }
    }
    // ---- T side: scan, scatter to LDS, stream out ----
    sc[tid]       = (tid < BT) ? cT[tid] : 0;
    sc[tid + 256] = (tid + 256 < BT) ? cT[tid + 256] : 0;
    __syncthreads();
    block_scan512(sc, tid);
    for (int b = tid; b < BT; b += 256) cur[b] = sc[b] - cT[b];
    __syncthreads();
#pragma unroll
    for (int k = 0; k < EPB / 256; ++k) {
        int i = e0 + k * 256 + tid;
        if (i < E) {
            int bt = ld[k] >> 8;
            int pos = atomicAdd(&cur[bt], 1);
            stage[pos] = ((unsigned)(ld[k] & 255) << LSHT) | (unsigned)ls[k];
        }
    }
    __syncthreads();
    for (int b = wave; b < BT; b += 4) {
        int cnt = cT[b], so = sc[b] - cnt, go = oT[b];
        for (int i = lane; i < cnt; i += 64) {
            int pos = go + i;
            if (pos < CAPB) binT[(size_t)b * CAPB + pos] = stage[so + i];
        }
    }
    __syncthreads();
    // ---- P side ----
    sc[tid]       = (tid < BP) ? cP[tid] : 0;
    sc[tid + 256] = (tid + 256 < BP) ? cP[tid + 256] : 0;
    __syncthreads();
    block_scan512(sc, tid);
    for (int b = tid; b < BP; b += 256) cur[b] = sc[b] - cP[b];
    __syncthreads();
#pragma unroll
    for (int k = 0; k < EPB / 256; ++k) {
        int i = e0 + k * 256 + tid;
        if (i < E) {
            int bp = ls[k] >> 9;
            int pos = atomicAdd(&cur[bp], 1);
            stage[pos] = ((unsigned)(ls[k] & 511) << LSHP) | (unsigned)ld[k];
        }
    }
    __syncthreads();
    for (int b = wave; b < BP; b += 4) {
        int cnt = cP[b], so = sc[b] - cnt, go = oP[b];
        for (int i = lane; i < cnt; i += 64) {
            int pos = go + i;
            if (pos < CAPB) binP[(size_t)b * CAPB + pos] = stage[so + i];
        }
    }
}

// ---- CSR per-bucket device body: scatter into LDS, stream out int4 -----
__device__ __forceinline__ void csr_dev(const unsigned* __restrict__ binned,
                                        const int* __restrict__ curPad,
                                        int* __restrict__ start_g, int* __restrict__ cnt_g,
                                        int* __restrict__ adj,
                                        int S, int lshift, int N, int b,
                                        int* lcnt, int* lscan, int* lcur, int* adj_lds) {
    int tid = threadIdx.x;
    int base = b * CAPB;
    int n = curPad[b * CURST]; if (n > CAPB) n = CAPB;
    int rowlo = b * S;
    unsigned nbmask = (1u << lshift) - 1u;

    for (int i = tid; i < S; i += 256) lcnt[i] = 0;
    __syncthreads();
    for (int i = tid; i < n; i += 256)
        atomicAdd(&lcnt[binned[base + i] >> lshift], 1);
    __syncthreads();
    for (int i = tid; i < S; i += 256) lscan[i] = lcnt[i];
    __syncthreads();
    for (int off = 1; off < S; off <<= 1) {
        int i0 = tid, i1 = tid + 256;
        int v0 = (i0 >= off) ? lscan[i0 - off] : 0;
        int v1 = (S > 256 && i1 >= off) ? lscan[i1 - off] : 0;
        __syncthreads();
        if (i0 < S) lscan[i0] += v0;
        if (S > 256 && i1 < S) lscan[i1] += v1;
        __syncthreads();
    }
    for (int r = tid; r < S; r += 256) {
        int ex = lscan[r] - lcnt[r];
        lcur[r] = ex;
        int row = rowlo + r;
        if (row < N) {
            start_g[row] = base + ex;
            cnt_g[row]   = lcnt[r];
        }
    }
    __syncthreads();
    for (int i = tid; i < n; i += 256) {
        unsigned e = binned[base + i];
        int r = e >> lshift;
        int pos = atomicAdd(&lcur[r], 1);
        adj_lds[pos] = (int)(e & nbmask);
    }
    __syncthreads();
    int n4 = n & ~3;
    for (int i = tid * 4; i < n4; i += 1024)
        *(int4*)&adj[base + i] = *(const int4*)&adj_lds[i];
    for (int i = n4 + tid; i < n; i += 256)
        adj[base + i] = adj_lds[i];
}

// ---- K_B: [csr-t | csr-p] ----------------------------------------------
__global__ void __launch_bounds__(256) k_csr(
    const unsigned* __restrict__ binT, const unsigned* __restrict__ binP,
    const int* __restrict__ curT, const int* __restrict__ curP,
    int* __restrict__ start_t, int* __restrict__ cnt_t, int* __restrict__ adj_t,
    int* __restrict__ start_p, int* __restrict__ cnt_p, int* __restrict__ adj_p,
    int BT, int BP, int NT_, int NP_) {
    __shared__ int lcnt[512], lscan[512], lcur[512];
    __shared__ int adj_lds[CAPB];
    int bi = blockIdx.x;
    if (bi < BT)
        csr_dev(binT, curT, start_t, cnt_t, adj_t, ST, LSHT, NT_, bi, lcnt, lscan, lcur, adj_lds);
    else
        csr_dev(binP, curP, start_p, cnt_p, adj_p, SP, LSHP, NP_, bi - BT, lcnt, lscan, lcur, adj_lds);
}

// ---- weight staging: pre-swizzled per-lane MFMA B-fragments into LDS ----
// layout: frag[(tbl*8 + kh*4 + nt)*64 + lane]; tbl0 = Wl, tbl1 = Wr
__device__ __forceinline__ void stage_w_lds(half8v* ldsW,
                                            const float* __restrict__ W1,
                                            const float* __restrict__ W2, int tid) {
    for (int f = tid; f < 1024; f += 256) {
        int lane = f & 63, nt = (f >> 6) & 3, kh = (f >> 8) & 1, tbl = f >> 9;
        int m = lane & 15, quad = lane >> 4;
        const float* W = tbl ? W2 : W1;
        half8v frag;
#pragma unroll
        for (int j = 0; j < 8; ++j) {
            int k = kh * 32 + quad * 8 + j;
            frag[j] = (_Float16)W[k * 64 + nt * 16 + m];
        }
        ldsW[f] = frag;
    }
}

// ---- fused gather-mean + dual-weight GEMM (mean@Wl + Self@Wr + b) ------
#define LDSC_STRIDE 72   // halves per row (144 B)
#define LDSC_TBL    1152 // halves per wave tile (16 rows)
__device__ __forceinline__ void gg_dev(
    const int* __restrict__ adj, const int* __restrict__ start, const int* __restrict__ cnt,
    const _Float16* __restrict__ G, const _Float16* __restrict__ S,
    const half8v* __restrict__ ldsW, _Float16* __restrict__ ldsC_w,
    const float* __restrict__ bias,
    _Float16* __restrict__ out, int N, int tile, int do_relu) {
    const int lane = threadIdx.x & 63;
    const int m = lane & 15, quad = lane >> 4;
    const int row = tile * 16 + m;

    half8v accl = {}, acch = {};
    int dg = 0;
    if (row < N) {
        int st = start[row];
        dg     = cnt[row];
        const half8v* G8 = (const half8v*)G;
        int j = 0;
        for (; j + 7 < dg; j += 8) {   // 8 neighbors x 2 chunks in flight
            int n[8];
#pragma unroll
            for (int k = 0; k < 8; ++k) n[k] = adj[st + j + k];
            half8v lv[8], hv[8];
#pragma unroll
            for (int k = 0; k < 8; ++k) {
                const half8v* rp = G8 + (size_t)n[k] * 8 + quad;
                lv[k] = rp[0];
                hv[k] = rp[4];
            }
            accl += ((lv[0] + lv[1]) + (lv[2] + lv[3])) + ((lv[4] + lv[5]) + (lv[6] + lv[7]));
            acch += ((hv[0] + hv[1]) + (hv[2] + hv[3])) + ((hv[4] + hv[5]) + (hv[6] + hv[7]));
        }
        if (j + 3 < dg) {
            int n[4];
#pragma unroll
            for (int k = 0; k < 4; ++k) n[k] = adj[st + j + k];
            half8v lv[4], hv[4];
#pragma unroll
            for (int k = 0; k < 4; ++k) {
                const half8v* rp = G8 + (size_t)n[k] * 8 + quad;
                lv[k] = rp[0];
                hv[k] = rp[4];
            }
            accl += (lv[0] + lv[1]) + (lv[2] + lv[3]);
            acch += (hv[0] + hv[1]) + (hv[2] + hv[3]);
            j += 4;
        }
        for (; j < dg; ++j) {
            const half8v* rp = G8 + (size_t)adj[st + j] * 8 + quad;
            accl += rp[0];
            acch += rp[4];
        }
    }

    f16x8 alo = {}, ahi = {}, slo = {}, shi = {};
    if (row < N) {
        float inv = 1.0f / (float)(dg > 1 ? dg : 1);
#pragma unroll
        for (int k = 0; k < 8; ++k) {
            alo[k] = (_Float16)((float)accl[k] * inv);
            ahi[k] = (_Float16)((float)acch[k] * inv);
        }
        const f16x8* S8 = (const f16x8*)S;
        slo = S8[(size_t)row * 8 + quad];       // self rows: hot gather table for
        shi = S8[(size_t)row * 8 + 4 + quad];   // the other side -> keep cached
    }

#pragma unroll
    for (int nt = 0; nt < 4; ++nt) {
        f16x8 wl_lo = (f16x8)ldsW[(0 * 8 + 0 * 4 + nt) * 64 + lane];
        f16x8 wl_hi = (f16x8)ldsW[(0 * 8 + 1 * 4 + nt) * 64 + lane];
        f16x8 wr_lo = (f16x8)ldsW[(1 * 8 + 0 * 4 + nt) * 64 + lane];
        f16x8 wr_hi = (f16x8)ldsW[(1 * 8 + 1 * 4 + nt) * 64 + lane];
        f32x4 a = {0.f, 0.f, 0.f, 0.f};
        a = MFMA16(alo, wl_lo, a);
        a = MFMA16(ahi, wl_hi, a);
        a = MFMA16(slo, wr_lo, a);
        a = MFMA16(shi, wr_hi, a);
        float bb = bias[nt * 16 + m];
#pragma unroll
        for (int r = 0; r < 4; ++r) {
            float v = a[r] + bb;
            if (do_relu) v = fmaxf(v, 0.f);
            ldsC_w[(quad * 4 + r) * LDSC_STRIDE + nt * 16 + m] = (_Float16)v;
        }
    }

    // coalesced store: lane -> (row = lane>>2, 16B chunk = lane&3), 2 halves
    {
        int rl = lane >> 2, ch = lane & 3;
        int orow = tile * 16 + rl;
        if (orow < N) {
#pragma unroll
            for (int half = 0; half < 2; ++half) {
                int lo = rl * LDSC_STRIDE + ch * 8 + half * 32;
                f16x8 v = *(const f16x8*)&ldsC_w[lo];
                *(f16x8*)&out[(size_t)orow * 64 + ch * 8 + half * 32] = v;
            }
        }
    }
}

// ---- K_C/K_D: fused [gather+dual GEMM], t | p --------------------------
__global__ void __launch_bounds__(256) k_gg(
    const int* __restrict__ adjT, const int* __restrict__ startT, const int* __restrict__ cntT,
    const _Float16* __restrict__ Gt, const _Float16* __restrict__ St,
    const float* __restrict__ Wlt, const float* __restrict__ Wrt, const float* __restrict__ bt,
    _Float16* __restrict__ outT, int NT_,
    const int* __restrict__ adjP, const int* __restrict__ startP, const int* __restrict__ cntP,
    const _Float16* __restrict__ Gp, const _Float16* __restrict__ Sp,
    const float* __restrict__ Wlp, const float* __restrict__ Wrp, const float* __restrict__ bp,
    _Float16* __restrict__ outP, int NP_,
    int tTB, int do_relu) {
    __shared__ half8v ldsW[1024];                            // 16 KiB weight fragments
    __shared__ __align__(16) _Float16 ldsC[4][LDSC_TBL];     // 9 KiB per-wave C tiles
    const int tid = threadIdx.x, wave = tid >> 6;
    if ((int)blockIdx.x < tTB) {
        stage_w_lds(ldsW, Wlt, Wrt, tid);
        __syncthreads();
        int tile = blockIdx.x * 4 + wave;
        if (tile < ((NT_ + 15) >> 4))
            gg_dev(adjT, startT, cntT, Gt, St, ldsW, ldsC[wave], bt, outT, NT_, tile, do_relu);
    } else {
        stage_w_lds(ldsW, Wlp, Wrp, tid);
        __syncthreads();
        int tile = (blockIdx.x - tTB) * 4 + wave;
        if (tile < ((NP_ + 15) >> 4))
            gg_dev(adjP, startP, cntP, Gp, Sp, ldsW, ldsC[wave], bp, outP, NP_, tile, do_relu);
    }
}

// ---- classifier: 8 lanes/edge, v_dot2_f32_f16 --------------------------
__global__ void __launch_bounds__(256) dot_h(const _Float16* __restrict__ p2,
                                             const _Float16* __restrict__ t2,
                                             const int* __restrict__ els,
                                             const int* __restrict__ eld,
                                             float* __restrict__ out, int EL) {
    int tid = blockIdx.x * 256 + threadIdx.x;
    int i = tid >> 3, c = tid & 7;
    if (i < EL) {
        int s = __builtin_nontemporal_load(&els[i]);
        int d = __builtin_nontemporal_load(&eld[i]);
        half8v a = ((const half8v*)p2)[(size_t)s * 8 + c];
        half8v b = ((const half8v*)t2)[(size_t)d * 8 + c];
        float v = 0.f;
#ifdef HAS_FDOT2
        const half2v* ap = (const half2v*)&a;
        const half2v* bp = (const half2v*)&b;
#pragma unroll
        for (int k = 0; k < 4; ++k) v = __builtin_amdgcn_fdot2(ap[k], bp[k], v, false);
#else
#pragma unroll
        for (int k = 0; k < 8; ++k) v += (float)a[k] * (float)b[k];
#endif
        v += __shfl_xor(v, 1, 64);
        v += __shfl_xor(v, 2, 64);
        v += __shfl_xor(v, 4, 64);
        if (c == 0) __builtin_nontemporal_store(v, &out[i]);
    }
}

extern "C" void kernel_launch(void* const* d_in, const int* in_sizes, int n_in,
                              void* d_out, int out_size, void* d_ws, size_t ws_size,
                              hipStream_t stream) {
    const float* x_taxon  = (const float*)d_in[0];
    const float* tlw      = (const float*)d_in[1];
    const float* tlb      = (const float*)d_in[2];
    const float* pemb     = (const float*)d_in[3];
    const float* temb     = (const float*)d_in[4];
    const int*   edge_src = (const int*)d_in[7];
    const int*   edge_dst = (const int*)d_in[8];
    const int*   el_src   = (const int*)d_in[9];
    const int*   el_dst   = (const int*)d_in[10];
    const float* c1pt_wl  = (const float*)d_in[11];
    const float* c1pt_wr  = (const float*)d_in[12];
    const float* c1tp_wl  = (const float*)d_in[13];
    const float* c1tp_wr  = (const float*)d_in[14];
    const float* c2pt_wl  = (const float*)d_in[15];
    const float* c2pt_wr  = (const float*)d_in[16];
    const float* c2tp_wl  = (const float*)d_in[17];
    const float* c2tp_wr  = (const float*)d_in[18];
    const float* c1pt_bl  = (const float*)d_in[19];
    const float* c1tp_bl  = (const float*)d_in[20];
    const float* c2pt_bl  = (const float*)d_in[21];
    const float* c2tp_bl  = (const float*)d_in[22];

    const int NP_ = in_sizes[5];
    const int NT_ = in_sizes[6];
    const int E_  = in_sizes[7];
    const int EL_ = in_sizes[9];
    const int BT  = (NT_ + ST - 1) / ST;   // 391
    const int BP  = (NP_ + SP - 1) / SP;   // 391

    // workspace (gather-then-transform: only raw feature tables live):
    //   XTh [NT]: K_A out (x@tlw+tlb+temb); L1-p gather table, L1-t self; t2 alias
    //   Ph  [NP]: K_A out (f16 pemb);       L1-t gather table, L1-p self; p2 alias
    //   t1  [NT]: L1 out; L2-p gather table, L2-t self
    //   p1  [NP]: L1 out; L2-t gather table, L2-p self
    _Float16* hb  = (_Float16*)d_ws;
    _Float16* XTh = hb;
    _Float16* Ph  = XTh + (size_t)NT_ * H;
    _Float16* t1  = Ph + (size_t)NP_ * H;
    _Float16* p1  = t1 + (size_t)NT_ * H;
    _Float16* t2  = XTh;   // alias: XTh dead after L1
    _Float16* p2  = Ph;    // alias: Ph dead after L1

    unsigned* binT    = (unsigned*)(p1 + (size_t)NP_ * H);   // BT*CAPB
    unsigned* binP    = binT + (size_t)BT * CAPB;            // BP*CAPB
    int*      adj_t   = (int*)(binP + (size_t)BP * CAPB);    // BT*CAPB
    int*      adj_p   = adj_t + (size_t)BT * CAPB;           // BP*CAPB
    int* start_t = adj_p + (size_t)BP * CAPB;  // NT
    int* start_p = start_t + NT_;              // NP
    int* cnt_t   = start_p + NP_;              // NT
    int* cnt_p   = cnt_t + NT_;                // NP
    int* curT    = cnt_p + NP_;                // BMAX*CURST (line-padded)
    int* curP    = curT + BMAX * CURST;        // BMAX*CURST

    (void)hipMemsetAsync(curT, 0, 2 * BMAX * CURST * sizeof(int), stream);

    const int nbBin = (E_ + EPB - 1) / EPB;              // 489
    const int XTB   = 512;                               // xt GEMM blocks
    const int CASTB = 256;                               // pemb cast blocks

    // K_A: bin + xt GEMM (XTh = x_taxon@tlw + tlb + temb) + pemb->f16 cast
    k_bin_xt<<<nbBin + XTB + CASTB, 256, 0, stream>>>(
        edge_src, edge_dst, curT, curP, binT, binP, BT, BP, E_, nbBin,
        x_taxon, tlw, tlb, temb, XTh, NT_, XTB, pemb, Ph, NP_, CASTB);

    // K_B: csr-t + csr-p
    k_csr<<<BT + BP, 256, 0, stream>>>(
        binT, binP, curT, curP,
        start_t, cnt_t, adj_t, start_p, cnt_p, adj_p, BT, BP, NT_, NP_);

    const int tTB = (((NT_ + 15) >> 4) + 3) >> 2;
    const int pTB = (((NP_ + 15) >> 4) + 3) >> 2;

    // L1: t1 = relu(mean(Ph[src])@c1pt_wl + XTh@c1pt_wr + c1pt_bl)
    //     p1 = relu(mean(XTh[dst])@c1tp_wl + Ph@c1tp_wr + c1tp_bl)
    k_gg<<<tTB + pTB, 256, 0, stream>>>(
        adj_t, start_t, cnt_t, Ph, XTh, c1pt_wl, c1pt_wr, c1pt_bl, t1, NT_,
        adj_p, start_p, cnt_p, XTh, Ph, c1tp_wl, c1tp_wr, c1tp_bl, p1, NP_,
        tTB, 1);

    // L2: t2 = mean(p1[src])@c2pt_wl + t1@c2pt_wr + c2pt_bl
    //     p2 = mean(t1[dst])@c2tp_wl + p1@c2tp_wr + c2tp_bl
    k_gg<<<tTB + pTB, 256, 0, stream>>>(
        adj_t, start_t, cnt_t, p1, t1, c2pt_wl, c2pt_wr, c2pt_bl, t2, NT_,
        adj_p, start_p, cnt_p, t1, p1, c2tp_wl, c2tp_wr, c2tp_bl, p2, NP_,
        tTB, 0);

    // classifier
    dot_h<<<(EL_ * 8 + 255) / 256, 256, 0, stream>>>(p2, t2, el_src, el_dst,
                                                     (float*)d_out, EL_);
}

// Round 16
// 445.671 us; speedup vs baseline: 1.1269x; 1.0121x over previous
//
#include <hip/hip_runtime.h>

#define H 64
#define EPB 4096        // edges per bin block (489 blocks)
#define BMAX 400        // >= bucket count (391)
#define ST 256          // taxon rows per bucket
#define SP 512          // palmprint rows per bucket
#define LSHT 18         // t-entry: (dst&255)<<18 | src
#define LSHP 17         // p-entry: (src&511)<<17 | dst
#define CAPB 5632       // bucket capacity (mean 5120 + 7 sigma); %4==0
#define CURST 16        // cur counter stride (64B: one counter per cache line)

typedef _Float16 half2v __attribute__((ext_vector_type(2)));
typedef _Float16 half8v __attribute__((ext_vector_type(8)));
typedef _Float16 f16x8  __attribute__((ext_vector_type(8)));
typedef float    f32x4  __attribute__((ext_vector_type(4)));
typedef int      i32x4  __attribute__((ext_vector_type(4)));

#if defined(__has_builtin)
#if __has_builtin(__builtin_amdgcn_fdot2)
#define HAS_FDOT2 1
#endif
#endif

#define MFMA16(a, b, c) __builtin_amdgcn_mfma_f32_16x16x32_f16(a, b, c, 0, 0, 0)

// ---- MFMA xt device body: C = A(f32)@W + bias + addend(f32), f16 out ----
__device__ __forceinline__ void mfma_xt_dev(const float* __restrict__ A,
                                            const float* __restrict__ W,
                                            const float* __restrict__ bias,
                                            const float* __restrict__ addend,
                                            _Float16* __restrict__ C,
                                            int N, int wid, int nwaves) {
    const int lane = threadIdx.x & 63;
    const int m = lane & 15, quad = lane >> 4;
    const int nTiles = (N + 15) >> 4;

    f16x8 wf[2][4];
#pragma unroll
    for (int kh = 0; kh < 2; ++kh)
#pragma unroll
        for (int nt = 0; nt < 4; ++nt) {
            f16x8 a;
#pragma unroll
            for (int j = 0; j < 8; ++j) {
                int k = kh * 32 + quad * 8 + j;
                a[j] = (_Float16)W[k * 64 + nt * 16 + m];
            }
            wf[kh][nt] = a;
        }
    float bv[4];
#pragma unroll
    for (int nt = 0; nt < 4; ++nt) bv[nt] = bias[nt * 16 + m];

    for (int t = wid; t < nTiles; t += nwaves) {
        int row = t * 16 + m;
        f16x8 alo = {}, ahi = {};
        if (row < N) {
            const f32x4* p = (const f32x4*)(A + (size_t)row * 64);
            f32x4 x0 = __builtin_nontemporal_load(p + quad * 2);
            f32x4 x1 = __builtin_nontemporal_load(p + quad * 2 + 1);
            f32x4 x2 = __builtin_nontemporal_load(p + 8 + quad * 2);
            f32x4 x3 = __builtin_nontemporal_load(p + 8 + quad * 2 + 1);
            alo[0] = (_Float16)x0[0]; alo[1] = (_Float16)x0[1];
            alo[2] = (_Float16)x0[2]; alo[3] = (_Float16)x0[3];
            alo[4] = (_Float16)x1[0]; alo[5] = (_Float16)x1[1];
            alo[6] = (_Float16)x1[2]; alo[7] = (_Float16)x1[3];
            ahi[0] = (_Float16)x2[0]; ahi[1] = (_Float16)x2[1];
            ahi[2] = (_Float16)x2[2]; ahi[3] = (_Float16)x2[3];
            ahi[4] = (_Float16)x3[0]; ahi[5] = (_Float16)x3[1];
            ahi[6] = (_Float16)x3[2]; ahi[7] = (_Float16)x3[3];
        }
#pragma unroll
        for (int nt = 0; nt < 4; ++nt) {
            f32x4 a1 = {0.f, 0.f, 0.f, 0.f};
            a1 = MFMA16(alo, wf[0][nt], a1);
            a1 = MFMA16(ahi, wf[1][nt], a1);
#pragma unroll
            for (int r = 0; r < 4; ++r) {
                int orow = t * 16 + quad * 4 + r;
                if (orow < N) {
                    float ad = __builtin_nontemporal_load(
                        &addend[(size_t)orow * 64 + nt * 16 + m]);
                    C[(size_t)orow * 64 + nt * 16 + m] = (_Float16)(a1[r] + bv[nt] + ad);
                }
            }
        }
    }
}

// in-place inclusive scan over sc[0..511] (counts pre-loaded), 256 threads
__device__ __forceinline__ void block_scan512(int* sc, int tid) {
    for (int off = 1; off < 512; off <<= 1) {
        int i0 = tid, i1 = tid + 256;
        int v0 = (i0 >= off) ? sc[i0 - off] : 0;
        int v1 = (i1 >= off) ? sc[i1 - off] : 0;
        __syncthreads();
        sc[i0] += v0;
        sc[i1] += v1;
        __syncthreads();
    }
}

// ---- K_A: fused [bin (rank-capture sort) | xt GEMM | pemb cast] --------
// Histogram atomics capture each edge's within-bucket rank, so the LDS
// scatter pass needs NO atomics (pos = excl_scan[bucket] + rank).
__global__ void __launch_bounds__(256) k_bin_xt(
    const int* __restrict__ src, const int* __restrict__ dst,
    int* __restrict__ curT, int* __restrict__ curP,
    unsigned* __restrict__ binT, unsigned* __restrict__ binP,
    int BT, int BP, int E, int nbBin,
    const float* __restrict__ A, const float* __restrict__ W,
    const float* __restrict__ bias, const float* __restrict__ addend,
    _Float16* __restrict__ C, int NT_, int xtBlocks,
    const float* __restrict__ pembIn, _Float16* __restrict__ PhOut,
    int NP_, int castBlocks) {
    __shared__ int cT[BMAX], cP[BMAX], oT[BMAX], oP[BMAX];
    __shared__ int sc[512];
    __shared__ unsigned stage[EPB];
    int tid = threadIdx.x;
    if ((int)blockIdx.x >= nbBin + xtBlocks) {
        // pemb f32 -> f16 cast (read-once stream)
        int cb = blockIdx.x - nbBin - xtBlocks;
        int idx = cb * 256 + tid, stride = castBlocks * 256;
        int total = NP_ * 8;
        for (int i = idx; i < total; i += stride) {
            const f32x4* p = (const f32x4*)(pembIn + (size_t)i * 8);
            f32x4 x0 = __builtin_nontemporal_load(p);
            f32x4 x1 = __builtin_nontemporal_load(p + 1);
            f16x8 o;
            o[0] = (_Float16)x0[0]; o[1] = (_Float16)x0[1];
            o[2] = (_Float16)x0[2]; o[3] = (_Float16)x0[3];
            o[4] = (_Float16)x1[0]; o[5] = (_Float16)x1[1];
            o[6] = (_Float16)x1[2]; o[7] = (_Float16)x1[3];
            *(f16x8*)&PhOut[(size_t)i * 8] = o;
        }
        return;
    }
    if ((int)blockIdx.x >= nbBin) {
        int xb = blockIdx.x - nbBin;
        mfma_xt_dev(A, W, bias, addend, C, NT_, xb * 4 + (tid >> 6), xtBlocks * 4);
        return;
    }
    const int wave = tid >> 6, lane = tid & 63;
    for (int i = tid; i < BMAX; i += 256) { cT[i] = 0; cP[i] = 0; }
    __syncthreads();
    int e0 = blockIdx.x * EPB;
    int ls[EPB / 256], ld[EPB / 256], rk[EPB / 256];  // rk = rankT | rankP<<16
#pragma unroll
    for (int k = 0; k < EPB / 256; ++k) {
        int i = e0 + k * 256 + tid;
        if (i < E) {
            ls[k] = __builtin_nontemporal_load(&src[i]);
            ld[k] = __builtin_nontemporal_load(&dst[i]);
            int rt = atomicAdd(&cT[ld[k] >> 8], 1);
            int rp = atomicAdd(&cP[ls[k] >> 9], 1);
            rk[k] = rt | (rp << 16);
        }
    }
    __syncthreads();
    // grab global chunks (padded counters + per-block rotated order)
    {
        int rotT = (int)((blockIdx.x * 53u) % (unsigned)BT);
        for (int b0 = tid; b0 < BT; b0 += 256) {
            int b = b0 + rotT; if (b >= BT) b -= BT;
            int c = cT[b]; oT[b] = c ? atomicAdd(&curT[b * CURST], c) : 0;
        }
        int rotP = (int)((blockIdx.x * 29u) % (unsigned)BP);
        for (int b0 = tid; b0 < BP; b0 += 256) {
            int b = b0 + rotP; if (b >= BP) b -= BP;
            int c = cP[b]; oP[b] = c ? atomicAdd(&curP[b * CURST], c) : 0;
        }
    }
    // ---- T side: scan, rank-scatter to LDS (no atomics), stream out ----
    sc[tid]       = (tid < BT) ? cT[tid] : 0;
    sc[tid + 256] = (tid + 256 < BT) ? cT[tid + 256] : 0;
    __syncthreads();
    block_scan512(sc, tid);
#pragma unroll
    for (int k = 0; k < EPB / 256; ++k) {
        int i = e0 + k * 256 + tid;
        if (i < E) {
            int bt = ld[k] >> 8;
            int pos = (sc[bt] - cT[bt]) + (rk[k] & 0xFFFF);
            stage[pos] = ((unsigned)(ld[k] & 255) << LSHT) | (unsigned)ls[k];
        }
    }
    __syncthreads();
    for (int b = wave; b < BT; b += 4) {
        int cnt = cT[b], so = sc[b] - cnt, go = oT[b];
        for (int i = lane; i < cnt; i += 64) {
            int pos = go + i;
            if (pos < CAPB) binT[(size_t)b * CAPB + pos] = stage[so + i];
        }
    }
    __syncthreads();
    // ---- P side ----
    sc[tid]       = (tid < BP) ? cP[tid] : 0;
    sc[tid + 256] = (tid + 256 < BP) ? cP[tid + 256] : 0;
    __syncthreads();
    block_scan512(sc, tid);
#pragma unroll
    for (int k = 0; k < EPB / 256; ++k) {
        int i = e0 + k * 256 + tid;
        if (i < E) {
            int bp = ls[k] >> 9;
            int pos = (sc[bp] - cP[bp]) + (rk[k] >> 16);
            stage[pos] = ((unsigned)(ls[k] & 511) << LSHP) | (unsigned)ld[k];
        }
    }
    __syncthreads();
    for (int b = wave; b < BP; b += 4) {
        int cnt = cP[b], so = sc[b] - cnt, go = oP[b];
        for (int i = lane; i < cnt; i += 64) {
            int pos = go + i;
            if (pos < CAPB) binP[(size_t)b * CAPB + pos] = stage[so + i];
        }
    }
}

// ---- CSR per-bucket device body: scatter into LDS, stream out int4 -----
__device__ __forceinline__ void csr_dev(const unsigned* __restrict__ binned,
                                        const int* __restrict__ curPad,
                                        int* __restrict__ start_g, int* __restrict__ cnt_g,
                                        int* __restrict__ adj,
                                        int S, int lshift, int N, int b,
                                        int* lcnt, int* lscan, int* lcur, int* adj_lds) {
    int tid = threadIdx.x;
    int base = b * CAPB;
    int n = curPad[b * CURST]; if (n > CAPB) n = CAPB;
    int rowlo = b * S;
    unsigned nbmask = (1u << lshift) - 1u;

    for (int i = tid; i < S; i += 256) lcnt[i] = 0;
    __syncthreads();
    for (int i = tid; i < n; i += 256)
        atomicAdd(&lcnt[binned[base + i] >> lshift], 1);
    __syncthreads();
    for (int i = tid; i < S; i += 256) lscan[i] = lcnt[i];
    __syncthreads();
    for (int off = 1; off < S; off <<= 1) {
        int i0 = tid, i1 = tid + 256;
        int v0 = (i0 >= off) ? lscan[i0 - off] : 0;
        int v1 = (S > 256 && i1 >= off) ? lscan[i1 - off] : 0;
        __syncthreads();
        if (i0 < S) lscan[i0] += v0;
        if (S > 256 && i1 < S) lscan[i1] += v1;
        __syncthreads();
    }
    for (int r = tid; r < S; r += 256) {
        int ex = lscan[r] - lcnt[r];
        lcur[r] = ex;
        int row = rowlo + r;
        if (row < N) {
            start_g[row] = base + ex;
            cnt_g[row]   = lcnt[r];
        }
    }
    __syncthreads();
    for (int i = tid; i < n; i += 256) {
        unsigned e = binned[base + i];
        int r = e >> lshift;
        int pos = atomicAdd(&lcur[r], 1);
        adj_lds[pos] = (int)(e & nbmask);
    }
    __syncthreads();
    int n4 = n & ~3;
    for (int i = tid * 4; i < n4; i += 1024)
        *(int4*)&adj[base + i] = *(const int4*)&adj_lds[i];
    for (int i = n4 + tid; i < n; i += 256)
        adj[base + i] = adj_lds[i];
}

// ---- K_B: [csr-t | csr-p] ----------------------------------------------
__global__ void __launch_bounds__(256) k_csr(
    const unsigned* __restrict__ binT, const unsigned* __restrict__ binP,
    const int* __restrict__ curT, const int* __restrict__ curP,
    int* __restrict__ start_t, int* __restrict__ cnt_t, int* __restrict__ adj_t,
    int* __restrict__ start_p, int* __restrict__ cnt_p, int* __restrict__ adj_p,
    int BT, int BP, int NT_, int NP_) {
    __shared__ int lcnt[512], lscan[512], lcur[512];
    __shared__ int adj_lds[CAPB];
    int bi = blockIdx.x;
    if (bi < BT)
        csr_dev(binT, curT, start_t, cnt_t, adj_t, ST, LSHT, NT_, bi, lcnt, lscan, lcur, adj_lds);
    else
        csr_dev(binP, curP, start_p, cnt_p, adj_p, SP, LSHP, NP_, bi - BT, lcnt, lscan, lcur, adj_lds);
}

// ---- weight staging: pre-swizzled per-lane MFMA B-fragments into LDS ----
// layout: frag[(tbl*8 + kh*4 + nt)*64 + lane]; tbl0 = Wl, tbl1 = Wr
__device__ __forceinline__ void stage_w_lds(half8v* ldsW,
                                            const float* __restrict__ W1,
                                            const float* __restrict__ W2, int tid) {
    for (int f = tid; f < 1024; f += 256) {
        int lane = f & 63, nt = (f >> 6) & 3, kh = (f >> 8) & 1, tbl = f >> 9;
        int m = lane & 15, quad = lane >> 4;
        const float* W = tbl ? W2 : W1;
        half8v frag;
#pragma unroll
        for (int j = 0; j < 8; ++j) {
            int k = kh * 32 + quad * 8 + j;
            frag[j] = (_Float16)W[k * 64 + nt * 16 + m];
        }
        ldsW[f] = frag;
    }
}

// ---- fused gather-mean + dual-weight GEMM (mean@Wl + Self@Wr + b) ------
#define LDSC_STRIDE 72   // halves per row (144 B)
#define LDSC_TBL    1152 // halves per wave tile (16 rows)
__device__ __forceinline__ void gg_dev(
    const int* __restrict__ adj, const int* __restrict__ start, const int* __restrict__ cnt,
    const _Float16* __restrict__ G, const _Float16* __restrict__ S,
    const half8v* __restrict__ ldsW, _Float16* __restrict__ ldsC_w,
    const float* __restrict__ bias,
    _Float16* __restrict__ out, int N, int tile, int do_relu) {
    const int lane = threadIdx.x & 63;
    const int m = lane & 15, quad = lane >> 4;
    const int row = tile * 16 + m;

    half8v accl = {}, acch = {};
    int dg = 0;
    if (row < N) {
        int st = start[row];
        dg     = cnt[row];
        const half8v* G8 = (const half8v*)G;
        int j = 0;
        for (; j + 7 < dg; j += 8) {   // 8 neighbors x 2 chunks in flight
            int n[8];
#pragma unroll
            for (int k = 0; k < 8; ++k) n[k] = adj[st + j + k];
            half8v lv[8], hv[8];
#pragma unroll
            for (int k = 0; k < 8; ++k) {
                const half8v* rp = G8 + (size_t)n[k] * 8 + quad;
                lv[k] = rp[0];
                hv[k] = rp[4];
            }
            accl += ((lv[0] + lv[1]) + (lv[2] + lv[3])) + ((lv[4] + lv[5]) + (lv[6] + lv[7]));
            acch += ((hv[0] + hv[1]) + (hv[2] + hv[3])) + ((hv[4] + hv[5]) + (hv[6] + hv[7]));
        }
        if (j + 3 < dg) {
            int n[4];
#pragma unroll
            for (int k = 0; k < 4; ++k) n[k] = adj[st + j + k];
            half8v lv[4], hv[4];
#pragma unroll
            for (int k = 0; k < 4; ++k) {
                const half8v* rp = G8 + (size_t)n[k] * 8 + quad;
                lv[k] = rp[0];
                hv[k] = rp[4];
            }
            accl += (lv[0] + lv[1]) + (lv[2] + lv[3]);
            acch += (hv[0] + hv[1]) + (hv[2] + hv[3]);
            j += 4;
        }
        for (; j < dg; ++j) {
            const half8v* rp = G8 + (size_t)adj[st + j] * 8 + quad;
            accl += rp[0];
            acch += rp[4];
        }
    }

    f16x8 alo = {}, ahi = {}, slo = {}, shi = {};
    if (row < N) {
        float inv = 1.0f / (float)(dg > 1 ? dg : 1);
#pragma unroll
        for (int k = 0; k < 8; ++k) {
            alo[k] = (_Float16)((float)accl[k] * inv);
            ahi[k] = (_Float16)((float)acch[k] * inv);
        }
        const f16x8* S8 = (const f16x8*)S;
        slo = S8[(size_t)row * 8 + quad];       // self rows: hot gather table for
        shi = S8[(size_t)row * 8 + 4 + quad];   // the other side -> keep cached
    }

#pragma unroll
    for (int nt = 0; nt < 4; ++nt) {
        f16x8 wl_lo = (f16x8)ldsW[(0 * 8 + 0 * 4 + nt) * 64 + lane];
        f16x8 wl_hi = (f16x8)ldsW[(0 * 8 + 1 * 4 + nt) * 64 + lane];
        f16x8 wr_lo = (f16x8)ldsW[(1 * 8 + 0 * 4 + nt) * 64 + lane];
        f16x8 wr_hi = (f16x8)ldsW[(1 * 8 + 1 * 4 + nt) * 64 + lane];
        f32x4 a = {0.f, 0.f, 0.f, 0.f};
        a = MFMA16(alo, wl_lo, a);
        a = MFMA16(ahi, wl_hi, a);
        a = MFMA16(slo, wr_lo, a);
        a = MFMA16(shi, wr_hi, a);
        float bb = bias[nt * 16 + m];
#pragma unroll
        for (int r = 0; r < 4; ++r) {
            float v = a[r] + bb;
            if (do_relu) v = fmaxf(v, 0.f);
            ldsC_w[(quad * 4 + r) * LDSC_STRIDE + nt * 16 + m] = (_Float16)v;
        }
    }

    // coalesced store: lane -> (row = lane>>2, 16B chunk = lane&3), 2 halves
    {
        int rl = lane >> 2, ch = lane & 3;
        int orow = tile * 16 + rl;
        if (orow < N) {
#pragma unroll
            for (int half = 0; half < 2; ++half) {
                int lo = rl * LDSC_STRIDE + ch * 8 + half * 32;
                f16x8 v = *(const f16x8*)&ldsC_w[lo];
                *(f16x8*)&out[(size_t)orow * 64 + ch * 8 + half * 32] = v;
            }
        }
    }
}

// ---- K_C/K_D: fused [gather+dual GEMM], t | p --------------------------
__global__ void __launch_bounds__(256) k_gg(
    const int* __restrict__ adjT, const int* __restrict__ startT, const int* __restrict__ cntT,
    const _Float16* __restrict__ Gt, const _Float16* __restrict__ St,
    const float* __restrict__ Wlt, const float* __restrict__ Wrt, const float* __restrict__ bt,
    _Float16* __restrict__ outT, int NT_,
    const int* __restrict__ adjP, const int* __restrict__ startP, const int* __restrict__ cntP,
    const _Float16* __restrict__ Gp, const _Float16* __restrict__ Sp,
    const float* __restrict__ Wlp, const float* __restrict__ Wrp, const float* __restrict__ bp,
    _Float16* __restrict__ outP, int NP_,
    int tTB, int do_relu) {
    __shared__ half8v ldsW[1024];                            // 16 KiB weight fragments
    __shared__ __align__(16) _Float16 ldsC[4][LDSC_TBL];     // 9 KiB per-wave C tiles
    const int tid = threadIdx.x, wave = tid >> 6;
    if ((int)blockIdx.x < tTB) {
        stage_w_lds(ldsW, Wlt, Wrt, tid);
        __syncthreads();
        int tile = blockIdx.x * 4 + wave;
        if (tile < ((NT_ + 15) >> 4))
            gg_dev(adjT, startT, cntT, Gt, St, ldsW, ldsC[wave], bt, outT, NT_, tile, do_relu);
    } else {
        stage_w_lds(ldsW, Wlp, Wrp, tid);
        __syncthreads();
        int tile = (blockIdx.x - tTB) * 4 + wave;
        if (tile < ((NP_ + 15) >> 4))
            gg_dev(adjP, startP, cntP, Gp, Sp, ldsW, ldsC[wave], bp, outP, NP_, tile, do_relu);
    }
}

// ---- classifier: 8 lanes/edge, v_dot2_f32_f16 --------------------------
__global__ void __launch_bounds__(256) dot_h(const _Float16* __restrict__ p2,
                                             const _Float16* __restrict__ t2,
                                             const int* __restrict__ els,
                                             const int* __restrict__ eld,
                                             float* __restrict__ out, int EL) {
    int tid = blockIdx.x * 256 + threadIdx.x;
    int i = tid >> 3, c = tid & 7;
    if (i < EL) {
        int s = __builtin_nontemporal_load(&els[i]);
        int d = __builtin_nontemporal_load(&eld[i]);
        half8v a = ((const half8v*)p2)[(size_t)s * 8 + c];
        half8v b = ((const half8v*)t2)[(size_t)d * 8 + c];
        float v = 0.f;
#ifdef HAS_FDOT2
        const half2v* ap = (const half2v*)&a;
        const half2v* bp = (const half2v*)&b;
#pragma unroll
        for (int k = 0; k < 4; ++k) v = __builtin_amdgcn_fdot2(ap[k], bp[k], v, false);
#else
#pragma unroll
        for (int k = 0; k < 8; ++k) v += (float)a[k] * (float)b[k];
#endif
        v += __shfl_xor(v, 1, 64);
        v += __shfl_xor(v, 2, 64);
        v += __shfl_xor(v, 4, 64);
        if (c == 0) __builtin_nontemporal_store(v, &out[i]);
    }
}

extern "C" void kernel_launch(void* const* d_in, const int* in_sizes, int n_in,
                              void* d_out, int out_size, void* d_ws, size_t ws_size,
                              hipStream_t stream) {
    const float* x_taxon  = (const float*)d_in[0];
    const float* tlw      = (const float*)d_in[1];
    const float* tlb      = (const float*)d_in[2];
    const float* pemb     = (const float*)d_in[3];
    const float* temb     = (const float*)d_in[4];
    const int*   edge_src = (const int*)d_in[7];
    const int*   edge_dst = (const int*)d_in[8];
    const int*   el_src   = (const int*)d_in[9];
    const int*   el_dst   = (const int*)d_in[10];
    const float* c1pt_wl  = (const float*)d_in[11];
    const float* c1pt_wr  = (const float*)d_in[12];
    const float* c1tp_wl  = (const float*)d_in[13];
    const float* c1tp_wr  = (const float*)d_in[14];
    const float* c2pt_wl  = (const float*)d_in[15];
    const float* c2pt_wr  = (const float*)d_in[16];
    const float* c2tp_wl  = (const float*)d_in[17];
    const float* c2tp_wr  = (const float*)d_in[18];
    const float* c1pt_bl  = (const float*)d_in[19];
    const float* c1tp_bl  = (const float*)d_in[20];
    const float* c2pt_bl  = (const float*)d_in[21];
    const float* c2tp_bl  = (const float*)d_in[22];

    const int NP_ = in_sizes[5];
    const int NT_ = in_sizes[6];
    const int E_  = in_sizes[7];
    const int EL_ = in_sizes[9];
    const int BT  = (NT_ + ST - 1) / ST;   // 391
    const int BP  = (NP_ + SP - 1) / SP;   // 391

    // workspace (gather-then-transform: only raw feature tables live):
    //   XTh [NT]: K_A out (x@tlw+tlb+temb); L1-p gather table, L1-t self; t2 alias
    //   Ph  [NP]: K_A out (f16 pemb);       L1-t gather table, L1-p self; p2 alias
    //   t1  [NT]: L1 out; L2-p gather table, L2-t self
    //   p1  [NP]: L1 out; L2-t gather table, L2-p self
    _Float16* hb  = (_Float16*)d_ws;
    _Float16* XTh = hb;
    _Float16* Ph  = XTh + (size_t)NT_ * H;
    _Float16* t1  = Ph + (size_t)NP_ * H;
    _Float16* p1  = t1 + (size_t)NT_ * H;
    _Float16* t2  = XTh;   // alias: XTh dead after L1
    _Float16* p2  = Ph;    // alias: Ph dead after L1

    unsigned* binT    = (unsigned*)(p1 + (size_t)NP_ * H);   // BT*CAPB
    unsigned* binP    = binT + (size_t)BT * CAPB;            // BP*CAPB
    int*      adj_t   = (int*)(binP + (size_t)BP * CAPB);    // BT*CAPB
    int*      adj_p   = adj_t + (size_t)BT * CAPB;           // BP*CAPB
    int* start_t = adj_p + (size_t)BP * CAPB;  // NT
    int* start_p = start_t + NT_;              // NP
    int* cnt_t   = start_p + NP_;              // NT
    int* cnt_p   = cnt_t + NT_;                // NP
    int* curT    = cnt_p + NP_;                // BMAX*CURST (line-padded)
    int* curP    = curT + BMAX * CURST;        // BMAX*CURST

    (void)hipMemsetAsync(curT, 0, 2 * BMAX * CURST * sizeof(int), stream);

    const int nbBin = (E_ + EPB - 1) / EPB;              // 489
    const int XTB   = 512;                               // xt GEMM blocks
    const int CASTB = 256;                               // pemb cast blocks

    // K_A: bin + xt GEMM (XTh = x_taxon@tlw + tlb + temb) + pemb->f16 cast
    k_bin_xt<<<nbBin + XTB + CASTB, 256, 0, stream>>>(
        edge_src, edge_dst, curT, curP, binT, binP, BT, BP, E_, nbBin,
        x_taxon, tlw, tlb, temb, XTh, NT_, XTB, pemb, Ph, NP_, CASTB);

    // K_B: csr-t + csr-p
    k_csr<<<BT + BP, 256, 0, stream>>>(
        binT, binP, curT, curP,
        start_t, cnt_t, adj_t, start_p, cnt_p, adj_p, BT, BP, NT_, NP_);

    const int tTB = (((NT_ + 15) >> 4) + 3) >> 2;
    const int pTB = (((NP_ + 15) >> 4) + 3) >> 2;

    // L1: t1 = relu(mean(Ph[src])@c1pt_wl + XTh@c1pt_wr + c1pt_bl)
    //     p1 = relu(mean(XTh[dst])@c1tp_wl + Ph@c1tp_wr + c1tp_bl)
    k_gg<<<tTB + pTB, 256, 0, stream>>>(
        adj_t, start_t, cnt_t, Ph, XTh, c1pt_wl, c1pt_wr, c1pt_bl, t1, NT_,
        adj_p, start_p, cnt_p, XTh, Ph, c1tp_wl, c1tp_wr, c1tp_bl, p1, NP_,
        tTB, 1);

    // L2: t2 = mean(p1[src])@c2pt_wl + t1@c2pt_wr + c2pt_bl
    //     p2 = mean(t1[dst])@c2tp_wl + p1@c2tp_wr + c2tp_bl
    k_gg<<<tTB + pTB, 256, 0, stream>>>(
        adj_t, start_t, cnt_t, p1, t1, c2pt_wl, c2pt_wr, c2pt_bl, t2, NT_,
        adj_p, start_p, cnt_p, t1, p1, c2tp_wl, c2tp_wr, c2tp_bl, p2, NP_,
        tTB, 0);

    // classifier
    dot_h<<<(EL_ * 8 + 255) / 256, 256, 0, stream>>>(p2, t2, el_src, el_dst,
                                                     (float*)d_out, EL_);
}